// Round 7
// baseline (3429366.406 us; speedup 1.0000x reference)
//
#include <hip/hip_runtime.h>

#define B_   256
#define HID  512
#define T_   32
#define L_   256
#define NC   97
#define G4   2048

// d_out layout (f32): g [256,32,97] | output_hiddens [256,32,512] | masks [256,32,8,32]
#define OH_OFF   794624
#define MASK_OFF 4988928

typedef __bf16 v8bf __attribute__((ext_vector_type(8)));
typedef float  v4f  __attribute__((ext_vector_type(4)));
typedef unsigned int v4u __attribute__((ext_vector_type(4)));

__device__ __forceinline__ unsigned short f2bf(float x){
  unsigned u = __float_as_uint(x);
  u += 0x7FFFu + ((u >> 16) & 1u);          // round-to-nearest-even
  return (unsigned short)(u >> 16);
}
__device__ __forceinline__ float bf2f(unsigned short h){
  return __uint_as_float(((unsigned)h) << 16);
}
__device__ __forceinline__ float sigm(float x){ return 1.f / (1.f + __expf(-x)); }
__device__ __forceinline__ float tanh_f(float x){
  float e = __expf(2.f * x);
  return 1.f - 2.f / (e + 1.f);             // safe at +/-inf
}
__device__ __forceinline__ v8bf ld8(const unsigned short* p){
  return *reinterpret_cast<const v8bf*>(p);
}

// L1-bypass (sc0) load: reads the XCD's L2 directly (fresh cross-CU data)
__device__ __forceinline__ unsigned ld_u32_sc0(const unsigned* p){
  unsigned v;
  asm volatile("global_load_dword %0, %1, off sc0\n\ts_waitcnt vmcnt(0)"
               : "=v"(v) : "v"(p) : "memory");
  return v;
}
// plain store + completion wait (write-through L1 -> L2)
__device__ __forceinline__ void st_u32_wait(unsigned* p, unsigned v){
  asm volatile("global_store_dword %0, %1, off\n\ts_waitcnt vmcnt(0)"
               :: "v"(p), "v"(v) : "memory");
}

// ---------------------------------------------------------------- one-time --
__global__ void k_wconv(const float* __restrict__ Whh0, const float* __restrict__ Wih1,
                        const float* __restrict__ Whh1, const float* __restrict__ Wih0,
                        unsigned short* __restrict__ Whh0bf, unsigned short* __restrict__ Wcat1bf,
                        unsigned short* __restrict__ Wih0bf){
  int i = blockIdx.x * 256 + threadIdx.x;
  if (i >= G4 * HID) return;
  Whh0bf[i] = f2bf(Whh0[i]);
  Wih0bf[i] = f2bf(Wih0[i]);
  int n = i >> 9, k = i & 511;
  Wcat1bf[(size_t)n * 1024 + k]       = f2bf(Wih1[i]);
  Wcat1bf[(size_t)n * 1024 + 512 + k] = f2bf(Whh1[i]);
}

__global__ void k_small(const float* __restrict__ embW, const float* __restrict__ embb,
                        const float* __restrict__ genW, const float* __restrict__ bih1,
                        const float* __restrict__ bhh1,
                        unsigned short* __restrict__ embXbf, unsigned short* __restrict__ genWbf,
                        float* __restrict__ b1sum){
  int i = blockIdx.x * 256 + threadIdx.x;
  if (i < NC * HID){
    int c = i >> 9, h = i & 511;
    embXbf[i] = f2bf(embW[h * NC + c] + embb[h]);
    genWbf[i] = f2bf(genW[i]);
  }
  if (i < G4) b1sum[i] = bih1[i] + bhh1[i];
}

// emb_gates[c][n] (MFMA, M=97 N=2048 K=512)
__global__ void __launch_bounds__(64)
k_embg_m(const unsigned short* __restrict__ embXbf, const unsigned short* __restrict__ Wih0bf,
         const float* __restrict__ bih0, const float* __restrict__ bhh0,
         float* __restrict__ embg){
  int m0 = blockIdx.x * 16, j0 = blockIdx.y * 16;
  int l = threadIdx.x, lr = l & 15, lk = l >> 4;
  int ar = min(m0 + lr, NC - 1);
  v4f acc = {0,0,0,0};
  for (int ks = 0; ks < 16; ++ks){
    int kb = ks * 32 + lk * 8;
    v8bf a  = ld8(embXbf + (size_t)ar * HID + kb);
    v8bf bf = ld8(Wih0bf + (size_t)(j0 + lr) * HID + kb);
    acc = __builtin_amdgcn_mfma_f32_16x16x32_bf16(a, bf, acc, 0, 0, 0);
  }
  int n = j0 + lr;
  float bb = bih0[n] + bhh0[n];
#pragma unroll
  for (int r = 0; r < 4; ++r){
    int c = m0 + lk * 4 + r;
    if (c < NC) embg[(size_t)c * G4 + n] = acc[r] + bb;
  }
}

// origin[b][c][l] f32 -> fmapT[b][l][c] bf16
__global__ void k_fmapT(const float* __restrict__ orig, unsigned short* __restrict__ fT){
  __shared__ float tile[32][33];
  int b = blockIdx.z, c0 = blockIdx.y * 32, l0 = blockIdx.x * 32;
  const float* src = orig + ((size_t)b * HID + c0) * L_ + l0;
  for (int i = 0; i < 32; i += 8)
    tile[threadIdx.y + i][threadIdx.x] = src[(threadIdx.y + i) * L_ + threadIdx.x];
  __syncthreads();
  unsigned short* dst = fT + ((size_t)b * L_ + l0) * HID + c0;
  for (int i = 0; i < 32; i += 8)
    dst[(threadIdx.y + i) * HID + threadIdx.x] = f2bf(tile[threadIdx.x][threadIdx.y + i]);
}

// ------------------------------------- XCD-local persistent pipelined LSTM --
// 256 blocks x 256 thr (cooperative, 1 block/CU forced by ~90KB LDS).
// Blocks read their REAL XCD id (HW_REG_XCC_ID) and claim a roster slot s on
// that XCD. Roles per XCD (32 blocks): s<16 -> LSTM0 (A), s>=16 -> LSTM1 (B);
// band = xcd + 8*((s&15)>>3) (batch rows band*16..+15), jgroup = s&7.
// Band->XCD alignment makes ALL h0/h1 producer/consumer pairs same-XCD:
// h exchange = plain write-through stores + sc0 (L1-bypass) loads via local L2;
// per-phase barrier is XCD-local (32 blocks, local-L2 flag protocol).
// No agent-scope traffic in the phase loop at all. c-state lives in VGPRs.
__global__ void __launch_bounds__(256, 1)
k_loop2(const unsigned short* __restrict__ Whh0bf,
        const unsigned short* __restrict__ Wcat1bf,
        const float* __restrict__ embg, const int* __restrict__ text,
        const float* __restrict__ b1sum,
        unsigned short* hx0, unsigned short* h1r,
        unsigned int* roster, unsigned int* flags, unsigned int* rel){
  const int SLOT = B_ * HID;
  const int tid = threadIdx.x;
  const int w = tid >> 6, l = tid & 63, lr = l & 15, lk = l >> 4;

  __shared__ unsigned short hS[16][1048];     // A: cols 0..511; B: h0|h1 0..1023
  __shared__ char lds_pad[56 * 1024];         // force 1 block/CU (no 2nd block fits)
  __shared__ int sh_xcd, sh_slot;

  if (roster == (unsigned int*)1) lds_pad[tid] = 1;   // keep lds_pad allocated

  if (tid == 0){
    unsigned x;
    asm volatile("s_getreg_b32 %0, hwreg(20, 0, 32)" : "=s"(x));  // HW_REG_XCC_ID
    x &= 7u;
    int s = (int)__hip_atomic_fetch_add(&roster[x * 16], 1u,
                                        __ATOMIC_RELAXED, __HIP_MEMORY_SCOPE_AGENT);
    sh_xcd = (int)x; sh_slot = s;
  }
  __syncthreads();
  const int xcd = sh_xcd;
  const int s   = sh_slot;
  if (s >= 32) return;                        // structurally impossible; safety

  const bool isB = s >= 16;
  const int sb   = s & 15;
  const int band = xcd + 8 * (sb >> 3);       // 0..15, band%8 == xcd
  const int jg   = sb & 7;
  const int m0   = band * 16;
  const int jw   = jg * 64 + w * 16;
  const int j    = jw + lr;

  float creg0 = 0.f, creg1 = 0.f, creg2 = 0.f, creg3 = 0.f;
  float xb0 = 0.f, xb1 = 0.f, xb2 = 0.f, xb3 = 0.f;
  if (isB){
    xb0 = b1sum[j]; xb1 = b1sum[512 + j];
    xb2 = b1sum[1024 + j]; xb3 = b1sum[1536 + j];
  }
  const unsigned short* W = isB ? Wcat1bf : Whh0bf;
  const int wstr = isB ? 1024 : 512;
  const int KS   = isB ? 32 : 16;

  for (int p = 0; p <= 32; ++p){
    const bool active = isB ? (p >= 1) : (p < 32);
    if (active){
      const int t = isB ? (p - 1) : p;
      const unsigned short* hA = hx0 + (size_t)(p & 1) * SLOT;     // h0(p)
      const unsigned short* hB = h1r + (size_t)(p - 1) * SLOT;     // h1(p-1)

      // ---- stage band rows into LDS via sc0 16B loads (local L2, fresh)
      v4u tmp[8];
      if (isB){
#pragma unroll
        for (int i = 0; i < 8; ++i){
          int e = tid + 256 * i;               // 0..2047
          int part = e >> 10, ei = e & 1023;
          int row = ei >> 6, c8 = (ei & 63) * 8;
          const unsigned short* src = (part ? hB : hA) + (size_t)(m0 + row) * HID + c8;
          asm volatile("global_load_dwordx4 %0, %1, off sc0"
                       : "=v"(tmp[i]) : "v"(src) : "memory");
        }
      } else {
#pragma unroll
        for (int i = 0; i < 4; ++i){
          int e = tid + 256 * i;               // 0..1023
          int row = e >> 6, c8 = (e & 63) * 8;
          const unsigned short* src = hA + (size_t)(m0 + row) * HID + c8;
          asm volatile("global_load_dwordx4 %0, %1, off sc0"
                       : "=v"(tmp[i]) : "v"(src) : "memory");
        }
      }
      asm volatile("s_waitcnt vmcnt(0)" ::: "memory");
      __builtin_amdgcn_sched_barrier(0);
      if (isB){
#pragma unroll
        for (int i = 0; i < 8; ++i){
          int e = tid + 256 * i;
          int part = e >> 10, ei = e & 1023;
          int row = ei >> 6, c8 = (ei & 63) * 8;
          *(v4u*)&hS[row][part * 512 + c8] = tmp[i];
        }
      } else {
#pragma unroll
        for (int i = 0; i < 4; ++i){
          int e = tid + 256 * i;
          int row = e >> 6, c8 = (e & 63) * 8;
          *(v4u*)&hS[row][c8] = tmp[i];
        }
      }
      __syncthreads();

      // ---- MFMA: 16 rows x 16 j x 4 gates, full K (hS col == kb for A and B)
      v4f acc0 = {0,0,0,0}, acc1 = {0,0,0,0}, acc2 = {0,0,0,0}, acc3 = {0,0,0,0};
#pragma unroll 4
      for (int ks = 0; ks < KS; ++ks){
        const int kb = ks * 32 + lk * 8;
        v8bf a  = *(const v8bf*)&hS[lr][kb];
        v8bf b0 = ld8(W + (size_t)(0 * HID + jw + lr) * wstr + kb);
        v8bf b1 = ld8(W + (size_t)(1 * HID + jw + lr) * wstr + kb);
        v8bf b2 = ld8(W + (size_t)(2 * HID + jw + lr) * wstr + kb);
        v8bf b3 = ld8(W + (size_t)(3 * HID + jw + lr) * wstr + kb);
        acc0 = __builtin_amdgcn_mfma_f32_16x16x32_bf16(a, b0, acc0, 0, 0, 0);
        acc1 = __builtin_amdgcn_mfma_f32_16x16x32_bf16(a, b1, acc1, 0, 0, 0);
        acc2 = __builtin_amdgcn_mfma_f32_16x16x32_bf16(a, b2, acc2, 0, 0, 0);
        acc3 = __builtin_amdgcn_mfma_f32_16x16x32_bf16(a, b3, acc3, 0, 0, 0);
      }

      unsigned short* hout = isB ? (h1r + (size_t)p * SLOT)             // h1(p)
                                 : (hx0 + (size_t)((p + 1) & 1) * SLOT);// h0(p+1)
#pragma unroll
      for (int r = 0; r < 4; ++r){
        const int brow = m0 + lk * 4 + r;
        float xi, xf, xg, xo;
        if (!isB){
          const float* eg = embg + (size_t)text[brow * T_ + t] * G4 + j;
          xi = eg[0]; xf = eg[512]; xg = eg[1024]; xo = eg[1536];
        } else {
          xi = xb0; xf = xb1; xg = xb2; xo = xb3;
        }
        float ig = acc0[r] + xi, fg = acc1[r] + xf;
        float gg = acc2[r] + xg, og = acc3[r] + xo;
        float cprev = (r == 0) ? creg0 : (r == 1) ? creg1 : (r == 2) ? creg2 : creg3;
        float cn = sigm(fg) * cprev + sigm(ig) * tanh_f(gg);
        if (r == 0) creg0 = cn; else if (r == 1) creg1 = cn;
        else if (r == 2) creg2 = cn; else creg3 = cn;
        float hn = sigm(og) * tanh_f(cn);
        unsigned v = f2bf(hn);
        unsigned pv = (unsigned)__shfl_xor((int)v, 1);      // partner col
        if (!(lr & 1)){
          unsigned pack = (v & 0xFFFFu) | (pv << 16);       // cols (j, j+1)
          *(unsigned*)(hout + (size_t)brow * HID + j) = pack;   // plain -> local L2
        }
      }
    }
    // ---- XCD-local barrier (32 blocks): arrive -> slot0 aggregates -> release
    if (p != 32){
      const unsigned tgt = (unsigned)(p + 1);
      __syncthreads();                        // drains vmcnt: h-stores in L2
      if (tid == 0)
        st_u32_wait(&flags[(xcd * 32 + s) * 16], tgt);
      if (s == 0){
        if (tid < 32){
          const unsigned* fp = &flags[(xcd * 32 + tid) * 16];
          unsigned it = 0;
          while (ld_u32_sc0(fp) < tgt){
            if (++it > 1000000u) break;
            __builtin_amdgcn_s_sleep(1);
          }
        }
        __syncthreads();
        if (tid == 0) st_u32_wait(&rel[xcd * 16], tgt);
      } else {
        if (tid == 0){
          const unsigned* rp = &rel[xcd * 16];
          unsigned it = 0;
          while (ld_u32_sc0(rp) < tgt){
            if (++it > 1000000u) break;
            __builtin_amdgcn_s_sleep(1);
          }
        }
        __syncthreads();
      }
    }
  }
}

// ---------------------------------------------------- per-step LSTM (fallback)
template<int MODE>
__global__ void __launch_bounds__(64)
k_lstm2(const unsigned short* __restrict__ hA1, const unsigned short* __restrict__ hA2,
        const unsigned short* __restrict__ Wbf,
        const float* __restrict__ embg, const int* __restrict__ text,
        const float* __restrict__ b1sum,
        float* __restrict__ cstate, unsigned short* __restrict__ hout,
        unsigned short* __restrict__ h1r, int t){
  const int KS = MODE ? 32 : 16;
  const int wstr = MODE ? 1024 : 512;
  int m0 = blockIdx.x * 32, j0 = blockIdx.y * 16;
  int l = threadIdx.x, lr = l & 15, lk = l >> 4;
  v4f acc[2][4] = {};
  for (int ks = 0; ks < KS; ++ks){
    int kb = ks * 32 + lk * 8;
    const unsigned short* Ap = (MODE == 1 && ks >= 16) ? hA2 : hA1;
    int ka = (MODE == 1 && ks >= 16) ? (kb - 512) : kb;
    v8bf a0 = ld8(Ap + (size_t)(m0 + lr) * HID + ka);
    v8bf a1 = ld8(Ap + (size_t)(m0 + 16 + lr) * HID + ka);
#pragma unroll
    for (int g = 0; g < 4; ++g){
      v8bf bf = ld8(Wbf + (size_t)(g * HID + j0 + lr) * wstr + kb);
      acc[0][g] = __builtin_amdgcn_mfma_f32_16x16x32_bf16(a0, bf, acc[0][g], 0, 0, 0);
      acc[1][g] = __builtin_amdgcn_mfma_f32_16x16x32_bf16(a1, bf, acc[1][g], 0, 0, 0);
    }
  }
  int j = j0 + lr;
  float xi = 0.f, xf = 0.f, xg = 0.f, xo = 0.f;
  if (MODE == 1){
    xi = b1sum[j]; xf = b1sum[512 + j]; xg = b1sum[1024 + j]; xo = b1sum[1536 + j];
  }
#pragma unroll
  for (int fm = 0; fm < 2; ++fm){
#pragma unroll
    for (int r = 0; r < 4; ++r){
      int b = m0 + fm * 16 + lk * 4 + r;
      if (MODE == 0){
        const float* eg = embg + (size_t)text[b * T_ + t] * G4 + j;
        xi = eg[0]; xf = eg[512]; xg = eg[1024]; xo = eg[1536];
      }
      float ig = acc[fm][0][r] + xi, fg = acc[fm][1][r] + xf;
      float gg = acc[fm][2][r] + xg, og = acc[fm][3][r] + xo;
      size_t sidx = (size_t)b * HID + j;
      float cn = sigm(fg) * cstate[sidx] + sigm(ig) * tanh_f(gg);
      cstate[sidx] = cn;
      float hn = sigm(og) * tanh_f(cn);
      hout[sidx] = f2bf(hn);
      if (MODE == 1 && h1r != nullptr)
        h1r[((size_t)(t + 1) * B_ + b) * HID + j] = f2bf(hn);  // ring layout
    }
  }
}

// ----------------------------------------------------- batched attention ----
__global__ void __launch_bounds__(256)
k_attn1(const unsigned short* __restrict__ fT, const unsigned short* __restrict__ h1r,
        float* __restrict__ d_out){
  int b = blockIdx.x, tid = threadIdx.x, w = tid >> 6, l = tid & 63;
  int lr = l & 15, lk = l >> 4;
  const unsigned short* fb = fT + (size_t)b * L_ * HID;
  v4f acc[2][4] = {};
  for (int ks = 0; ks < 16; ++ks){
    int kb = ks * 32 + lk * 8;
    v8bf a0 = ld8(h1r + ((size_t)(lr + 1)  * B_ + b) * HID + kb);   // t = lr
    v8bf a1 = ld8(h1r + ((size_t)(lr + 17) * B_ + b) * HID + kb);   // t = 16+lr
#pragma unroll
    for (int fn = 0; fn < 4; ++fn){
      v8bf bf = ld8(fb + (size_t)(w * 64 + fn * 16 + lr) * HID + kb);
      acc[0][fn] = __builtin_amdgcn_mfma_f32_16x16x32_bf16(a0, bf, acc[0][fn], 0, 0, 0);
      acc[1][fn] = __builtin_amdgcn_mfma_f32_16x16x32_bf16(a1, bf, acc[1][fn], 0, 0, 0);
    }
  }
#pragma unroll
  for (int fm = 0; fm < 2; ++fm)
#pragma unroll
    for (int fn = 0; fn < 4; ++fn)
#pragma unroll
      for (int r = 0; r < 4; ++r){
        int tt = fm * 16 + lk * 4 + r;
        int li = w * 64 + fn * 16 + lr;
        d_out[MASK_OFF + ((size_t)b * T_ + tt) * L_ + li] = sigm(acc[fm][fn][r]);
      }
}

__global__ void __launch_bounds__(512)
k_attn2(const unsigned short* __restrict__ fT, const float* __restrict__ d_out_ro,
        float* __restrict__ d_out, unsigned short* __restrict__ ctxbf){
  int b = blockIdx.x, tid = threadIdx.x, w = tid >> 6, l = tid & 63;
  __shared__ float aS[T_][L_];
  const float* ab = d_out_ro + MASK_OFF + (size_t)b * T_ * L_;
  for (int i = tid * 4; i < T_ * L_; i += 512 * 4){
    float4 v = *(const float4*)(ab + i);
    int tt = i >> 8, ll = i & 255;
    aS[tt][ll+0] = v.x; aS[tt][ll+1] = v.y; aS[tt][ll+2] = v.z; aS[tt][ll+3] = v.w;
  }
  __syncthreads();
  float acc[4][8] = {};
  const unsigned short* fb = fT + (size_t)b * L_ * HID + l * 8;
  for (int li = 0; li < L_; ++li){
    ushort4 u0 = *(const ushort4*)(fb + (size_t)li * HID);
    ushort4 u1 = *(const ushort4*)(fb + (size_t)li * HID + 4);
    float f[8] = {bf2f(u0.x), bf2f(u0.y), bf2f(u0.z), bf2f(u0.w),
                  bf2f(u1.x), bf2f(u1.y), bf2f(u1.z), bf2f(u1.w)};
#pragma unroll
    for (int tt = 0; tt < 4; ++tt){
      float a = aS[w * 4 + tt][li];
#pragma unroll
      for (int k = 0; k < 8; ++k) acc[tt][k] += a * f[k];
    }
  }
#pragma unroll
  for (int tt = 0; tt < 4; ++tt)
#pragma unroll
    for (int k = 0; k < 8; ++k){
      size_t o = ((size_t)b * T_ + w * 4 + tt) * HID + l * 8 + k;
      d_out[OH_OFF + o] = acc[tt][k];
      ctxbf[o] = f2bf(acc[tt][k]);
    }
}

// ------------------------------------------------------------------ final ---
__global__ void __launch_bounds__(256)
k_gen_m(const unsigned short* __restrict__ ctxbf, const unsigned short* __restrict__ genWbf,
        const float* __restrict__ genb, float* __restrict__ g){
  int m0 = blockIdx.x * 64 + (threadIdx.x >> 6) * 16;
  int j0 = blockIdx.y * 16;
  int l = threadIdx.x & 63, lr = l & 15, lk = l >> 4;
  int n = j0 + lr, nr = min(n, NC - 1);
  v4f acc = {0,0,0,0};
  for (int ks = 0; ks < 16; ++ks){
    int kb = ks * 32 + lk * 8;
    v8bf a  = ld8(ctxbf + (size_t)(m0 + lr) * HID + kb);
    v8bf bf = ld8(genWbf + (size_t)nr * HID + kb);
    acc = __builtin_amdgcn_mfma_f32_16x16x32_bf16(a, bf, acc, 0, 0, 0);
  }
  if (n < NC){
    float bb = genb[n];
#pragma unroll
    for (int r = 0; r < 4; ++r)
      g[(size_t)(m0 + lk * 4 + r) * NC + n] = acc[r] + bb;
  }
}

// --------------------------------------------------------------- fallbacks --
__global__ void __launch_bounds__(256)
k_attn_direct(const float* __restrict__ orig, const unsigned short* __restrict__ h1b,
              float* __restrict__ d_out, int t){
  int b = blockIdx.x, tid = threadIdx.x;
  __shared__ float h1s[HID];
  __shared__ float as[L_];
  h1s[tid]       = bf2f(h1b[(size_t)b * HID + tid]);
  h1s[256 + tid] = bf2f(h1b[(size_t)b * HID + 256 + tid]);
  __syncthreads();
  const float* fb = orig + (size_t)b * HID * L_;
  float dot = 0.f;
  for (int ch = 0; ch < HID; ++ch) dot += h1s[ch] * fb[(size_t)ch * L_ + tid];
  float a = sigm(dot);
  as[tid] = a;
  d_out[MASK_OFF + ((size_t)b * T_ + t) * L_ + tid] = a;
  __syncthreads();
  for (int cc = 0; cc < 2; ++cc){
    int ch = tid + cc * 256;
    float s = 0.f;
    for (int ll = 0; ll < L_; ++ll) s += as[ll] * fb[(size_t)ch * L_ + ll];
    d_out[OH_OFF + ((size_t)b * T_ + t) * HID + ch] = s;
  }
}

__global__ void k_gen_v(const float* __restrict__ ctx, const float* __restrict__ genW,
                        const float* __restrict__ genb, float* __restrict__ g){
  int o = blockIdx.x * 256 + threadIdx.x;
  if (o >= B_ * T_ * NC) return;
  int m = o / NC, n = o - m * NC;
  const float4* a = (const float4*)(ctx + (size_t)m * HID);
  const float4* wv = (const float4*)(genW + (size_t)n * HID);
  float s = genb[n];
  for (int k = 0; k < HID / 4; ++k){
    float4 av = a[k], w = wv[k];
    s += av.x * w.x + av.y * w.y + av.z * w.z + av.w * w.w;
  }
  g[o] = s;
}

// -----------------------------------------------------------------------------
extern "C" void kernel_launch(void* const* d_in, const int* in_sizes, int n_in,
                              void* d_out, int out_size, void* d_ws, size_t ws_size,
                              hipStream_t stream){
  const float* orig = (const float*)d_in[0];
  const int*   text = (const int*)  d_in[1];
  const float* embW = (const float*)d_in[2];
  const float* embb = (const float*)d_in[3];
  const float* Wih0 = (const float*)d_in[4];
  const float* Whh0 = (const float*)d_in[5];
  const float* bih0 = (const float*)d_in[6];
  const float* bhh0 = (const float*)d_in[7];
  const float* Wih1 = (const float*)d_in[8];
  const float* Whh1 = (const float*)d_in[9];
  const float* bih1 = (const float*)d_in[10];
  const float* bhh1 = (const float*)d_in[11];
  const float* genW = (const float*)d_in[12];
  const float* genb = (const float*)d_in[13];
  float* out = (float*)d_out;

  const size_t SLOTB = (size_t)B_ * HID * 2;          // 256 KB

  char* p = (char*)d_ws;
  float* embg  = (float*)p;           p += (size_t)NC * G4 * 4;
  float* b1sum = (float*)p;           p += (size_t)G4 * 4;
  // ---- zero-init region ----
  unsigned short* hx0 = (unsigned short*)p;    p += 2 * SLOTB;      // h0 ping-pong
  unsigned int* roster = (unsigned int*)p;     p += 8 * 64;
  unsigned int* flags  = (unsigned int*)p;     p += 256 * 64;
  unsigned int* rel    = (unsigned int*)p;     p += 8 * 64;
  unsigned short* h0p0 = (unsigned short*)p;   p += SLOTB;          // fallback
  unsigned short* h0p1 = (unsigned short*)p;   p += SLOTB;
  unsigned short* h1p0 = (unsigned short*)p;   p += SLOTB;
  unsigned short* h1p1 = (unsigned short*)p;   p += SLOTB;
  float* c0 = (float*)p;                       p += (size_t)B_ * HID * 4;
  float* c1 = (float*)p;                       p += (size_t)B_ * HID * 4;
  size_t zbytes = (size_t)((char*)p - (char*)hx0);
  // ---- end zero region ----
  unsigned short* Whh0bf  = (unsigned short*)p; p += (size_t)G4 * 512 * 2;
  unsigned short* Wcat1bf = (unsigned short*)p; p += (size_t)G4 * 1024 * 2;
  unsigned short* Wih0bf  = (unsigned short*)p; p += (size_t)G4 * 512 * 2;
  unsigned short* embXbf  = (unsigned short*)p; p += (size_t)NC * HID * 2;
  unsigned short* genWbf  = (unsigned short*)p; p += (size_t)NC * HID * 2;
  unsigned short* h1r = (unsigned short*)p;    p += 33 * SLOTB;     // h1 ring (8.25MB)
  unsigned short* ctxbf = (unsigned short*)p;  p += (size_t)B_ * T_ * HID * 2;  // 8MB
  unsigned short* fmapT = (unsigned short*)p;  p += (size_t)B_ * L_ * HID * 2;  // 64MB
  bool big = ws_size >= (size_t)(p - (char*)d_ws);

  hipMemsetAsync(hx0, 0, zbytes, stream);
  if (big) hipMemsetAsync(h1r, 0, SLOTB, stream);     // h1(0) = zeros

  k_wconv<<<(G4 * HID + 255) / 256, 256, 0, stream>>>(Whh0, Wih1, Whh1, Wih0,
                                                      Whh0bf, Wcat1bf, Wih0bf);
  k_small<<<(NC * HID + 255) / 256, 256, 0, stream>>>(embW, embb, genW, bih1, bhh1,
                                                      embXbf, genWbf, b1sum);
  k_embg_m<<<dim3(7, G4 / 16), 64, 0, stream>>>(embXbf, Wih0bf, bih0, bhh0, embg);
  if (big) k_fmapT<<<dim3(L_ / 32, HID / 32, B_), dim3(32, 8), 0, stream>>>(orig, fmapT);

  hipError_t ce = hipErrorUnknown;
  if (big){
    const unsigned short* a0 = Whh0bf; const unsigned short* a1 = Wcat1bf;
    const float* a2 = embg; const int* a3 = text; const float* a4 = b1sum;
    unsigned short* a5 = hx0; unsigned short* a6 = h1r;
    unsigned int* a7 = roster; unsigned int* a8 = flags; unsigned int* a9 = rel;
    void* args[] = {&a0, &a1, &a2, &a3, &a4, &a5, &a6, &a7, &a8, &a9};
    ce = hipLaunchCooperativeKernel((const void*)k_loop2, dim3(256), dim3(256),
                                    args, 0, stream);
  }
  if (ce != hipSuccess){
    // fallback: per-step kernels
    unsigned short* h0bf[2] = {h0p0, h0p1};
    unsigned short* h1bf[2] = {h1p0, h1p1};
    for (int t = 0; t < T_; ++t){
      int ping = t & 1;
      k_lstm2<0><<<dim3(8, 32), 64, 0, stream>>>(h0bf[ping], nullptr, Whh0bf,
          embg, text, nullptr, c0, h0bf[ping ^ 1], nullptr, t);
      k_lstm2<1><<<dim3(8, 32), 64, 0, stream>>>(h0bf[ping ^ 1], h1bf[ping], Wcat1bf,
          nullptr, nullptr, b1sum, c1, h1bf[ping ^ 1], big ? h1r : nullptr, t);
      if (!big) k_attn_direct<<<B_, 256, 0, stream>>>(orig, h1bf[ping ^ 1], out, t);
    }
  }

  if (big){
    k_attn1<<<B_, 256, 0, stream>>>(fmapT, h1r, out);
    k_attn2<<<B_, 512, 0, stream>>>(fmapT, (const float*)out, out, ctxbf);
    k_gen_m<<<dim3(B_ * T_ / 64, 7), 256, 0, stream>>>(ctxbf, genWbf, genb, out);
  } else {
    k_gen_v<<<(B_ * T_ * NC + 255) / 256, 256, 0, stream>>>(out + OH_OFF, genW, genb, out);
  }
}

// Round 8
// 1454.366 us; speedup vs baseline: 2357.9797x; 2357.9797x over previous
//
#include <hip/hip_runtime.h>

#define B_   256
#define HID  512
#define T_   32
#define L_   256
#define NC   97
#define G4   2048

// d_out layout (f32): g [256,32,97] | output_hiddens [256,32,512] | masks [256,32,8,32]
#define OH_OFF   794624
#define MASK_OFF 4988928

typedef __bf16 v8bf __attribute__((ext_vector_type(8)));
typedef float  v4f  __attribute__((ext_vector_type(4)));
typedef unsigned int v4u __attribute__((ext_vector_type(4)));

__device__ __forceinline__ unsigned short f2bf(float x){
  unsigned u = __float_as_uint(x);
  u += 0x7FFFu + ((u >> 16) & 1u);          // round-to-nearest-even
  return (unsigned short)(u >> 16);
}
__device__ __forceinline__ float bf2f(unsigned short h){
  return __uint_as_float(((unsigned)h) << 16);
}
__device__ __forceinline__ float sigm(float x){ return 1.f / (1.f + __expf(-x)); }
__device__ __forceinline__ float tanh_f(float x){
  float e = __expf(2.f * x);
  return 1.f - 2.f / (e + 1.f);             // safe at +/-inf
}
__device__ __forceinline__ v8bf ld8(const unsigned short* p){
  return *reinterpret_cast<const v8bf*>(p);
}

// ---------------------------------------------------------------- one-time --
__global__ void k_wconv(const float* __restrict__ Whh0, const float* __restrict__ Wih1,
                        const float* __restrict__ Whh1, const float* __restrict__ Wih0,
                        unsigned short* __restrict__ Whh0bf, unsigned short* __restrict__ Wcat1bf,
                        unsigned short* __restrict__ Wih0bf){
  int i = blockIdx.x * 256 + threadIdx.x;
  if (i >= G4 * HID) return;
  Whh0bf[i] = f2bf(Whh0[i]);
  Wih0bf[i] = f2bf(Wih0[i]);
  int n = i >> 9, k = i & 511;
  Wcat1bf[(size_t)n * 1024 + k]       = f2bf(Wih1[i]);
  Wcat1bf[(size_t)n * 1024 + 512 + k] = f2bf(Whh1[i]);
}

__global__ void k_small(const float* __restrict__ embW, const float* __restrict__ embb,
                        const float* __restrict__ genW, const float* __restrict__ bih1,
                        const float* __restrict__ bhh1,
                        unsigned short* __restrict__ embXbf, unsigned short* __restrict__ genWbf,
                        float* __restrict__ b1sum){
  int i = blockIdx.x * 256 + threadIdx.x;
  if (i < NC * HID){
    int c = i >> 9, h = i & 511;
    embXbf[i] = f2bf(embW[h * NC + c] + embb[h]);
    genWbf[i] = f2bf(genW[i]);
  }
  if (i < G4) b1sum[i] = bih1[i] + bhh1[i];
}

// emb_gates[c][n] (MFMA, M=97 N=2048 K=512)
__global__ void __launch_bounds__(64)
k_embg_m(const unsigned short* __restrict__ embXbf, const unsigned short* __restrict__ Wih0bf,
         const float* __restrict__ bih0, const float* __restrict__ bhh0,
         float* __restrict__ embg){
  int m0 = blockIdx.x * 16, j0 = blockIdx.y * 16;
  int l = threadIdx.x, lr = l & 15, lk = l >> 4;
  int ar = min(m0 + lr, NC - 1);
  v4f acc = {0,0,0,0};
  for (int ks = 0; ks < 16; ++ks){
    int kb = ks * 32 + lk * 8;
    v8bf a  = ld8(embXbf + (size_t)ar * HID + kb);
    v8bf bf = ld8(Wih0bf + (size_t)(j0 + lr) * HID + kb);
    acc = __builtin_amdgcn_mfma_f32_16x16x32_bf16(a, bf, acc, 0, 0, 0);
  }
  int n = j0 + lr;
  float bb = bih0[n] + bhh0[n];
#pragma unroll
  for (int r = 0; r < 4; ++r){
    int c = m0 + lk * 4 + r;
    if (c < NC) embg[(size_t)c * G4 + n] = acc[r] + bb;
  }
}

// origin[b][c][l] f32 -> fmapT[b][l][c] bf16
__global__ void k_fmapT(const float* __restrict__ orig, unsigned short* __restrict__ fT){
  __shared__ float tile[32][33];
  int b = blockIdx.z, c0 = blockIdx.y * 32, l0 = blockIdx.x * 32;
  const float* src = orig + ((size_t)b * HID + c0) * L_ + l0;
  for (int i = 0; i < 32; i += 8)
    tile[threadIdx.y + i][threadIdx.x] = src[(threadIdx.y + i) * L_ + threadIdx.x];
  __syncthreads();
  unsigned short* dst = fT + ((size_t)b * L_ + l0) * HID + c0;
  for (int i = 0; i < 32; i += 8)
    dst[(threadIdx.y + i) * HID + threadIdx.x] = f2bf(tile[threadIdx.x][threadIdx.y + i]);
}

// ----------------------------------------------- fused per-step LSTM launch --
// Launched 33x (p = 0..32). Blocks 0..127: LSTM0 step p (skip if p==32).
// Blocks 128..255: LSTM1 step p-1 (skip if p==0). A and B are independent
// within a launch; all producer->consumer edges cross a kernel boundary, so
// plain cached loads/stores are coherent. No atomics, no barriers, no spins.
// Per block: 16-row m-band x (4 waves x 16 j) x all 4 gates; c-state in global.
__global__ void __launch_bounds__(256)
k_step(const unsigned short* __restrict__ Whh0bf,
       const unsigned short* __restrict__ Wcat1bf,
       const float* __restrict__ embg, const int* __restrict__ text,
       const float* __restrict__ b1sum,
       unsigned short* __restrict__ hx0, unsigned short* __restrict__ h1r,
       float* __restrict__ c0, float* __restrict__ c1, int p){
  const int SLOT = B_ * HID;
  const int bid = blockIdx.x;
  const bool isB = bid >= 128;
  if (isB ? (p < 1) : (p >= 32)) return;
  const int gb = bid & 127;
  const int tid = threadIdx.x;
  const int w = tid >> 6, l = tid & 63, lr = l & 15, lk = l >> 4;
  const int m0 = (gb >> 3) * 16;
  const int jw = (gb & 7) * 64 + w * 16;
  const int j  = jw + lr;
  const int t  = isB ? (p - 1) : p;

  __shared__ unsigned short hS[16][1048];    // A: cols 0..511; B: h0|h1 0..1023

  const unsigned short* hA = hx0 + (size_t)(p & 1) * SLOT;              // h0(p)
  const unsigned short* hB = h1r + (size_t)(isB ? (p - 1) : 0) * SLOT;  // h1(p-1)

  if (isB){
#pragma unroll
    for (int i = 0; i < 8; ++i){
      int e = tid + 256 * i;                 // 0..2047 (16B chunks)
      int part = e >> 10, ei = e & 1023;
      int row = ei >> 6, c8 = (ei & 63) * 8;
      const unsigned short* src = (part ? hB : hA) + (size_t)(m0 + row) * HID + c8;
      *(v4u*)&hS[row][part * 512 + c8] = *(const v4u*)src;
    }
  } else {
#pragma unroll
    for (int i = 0; i < 4; ++i){
      int e = tid + 256 * i;                 // 0..1023
      int row = e >> 6, c8 = (e & 63) * 8;
      *(v4u*)&hS[row][c8] = *(const v4u*)(hA + (size_t)(m0 + row) * HID + c8);
    }
  }
  __syncthreads();

  const unsigned short* W = isB ? Wcat1bf : Whh0bf;
  const int wstr = isB ? 1024 : 512;
  const int KS   = isB ? 32 : 16;
  v4f acc0 = {0,0,0,0}, acc1 = {0,0,0,0}, acc2 = {0,0,0,0}, acc3 = {0,0,0,0};
#pragma unroll 4
  for (int ks = 0; ks < KS; ++ks){
    const int kb = ks * 32 + lk * 8;
    v8bf a  = *(const v8bf*)&hS[lr][kb];
    v8bf b0 = ld8(W + (size_t)(0 * HID + jw + lr) * wstr + kb);
    v8bf b1 = ld8(W + (size_t)(1 * HID + jw + lr) * wstr + kb);
    v8bf b2 = ld8(W + (size_t)(2 * HID + jw + lr) * wstr + kb);
    v8bf b3 = ld8(W + (size_t)(3 * HID + jw + lr) * wstr + kb);
    acc0 = __builtin_amdgcn_mfma_f32_16x16x32_bf16(a, b0, acc0, 0, 0, 0);
    acc1 = __builtin_amdgcn_mfma_f32_16x16x32_bf16(a, b1, acc1, 0, 0, 0);
    acc2 = __builtin_amdgcn_mfma_f32_16x16x32_bf16(a, b2, acc2, 0, 0, 0);
    acc3 = __builtin_amdgcn_mfma_f32_16x16x32_bf16(a, b3, acc3, 0, 0, 0);
  }

  float xb0 = 0.f, xb1 = 0.f, xb2 = 0.f, xb3 = 0.f;
  if (isB){
    xb0 = b1sum[j]; xb1 = b1sum[512 + j];
    xb2 = b1sum[1024 + j]; xb3 = b1sum[1536 + j];
  }
  float* cst = isB ? c1 : c0;
  unsigned short* hout = isB ? (h1r + (size_t)p * SLOT)             // h1(p)
                             : (hx0 + (size_t)((p + 1) & 1) * SLOT);// h0(p+1)
#pragma unroll
  for (int r = 0; r < 4; ++r){
    const int brow = m0 + lk * 4 + r;
    float xi, xf, xg, xo;
    if (!isB){
      const float* eg = embg + (size_t)text[brow * T_ + t] * G4 + j;
      xi = eg[0]; xf = eg[512]; xg = eg[1024]; xo = eg[1536];
    } else {
      xi = xb0; xf = xb1; xg = xb2; xo = xb3;
    }
    float ig = acc0[r] + xi, fg = acc1[r] + xf;
    float gg = acc2[r] + xg, og = acc3[r] + xo;
    size_t ci = (size_t)brow * HID + j;
    float cn = sigm(fg) * cst[ci] + sigm(ig) * tanh_f(gg);
    cst[ci] = cn;
    float hn = sigm(og) * tanh_f(cn);
    unsigned v = f2bf(hn);
    unsigned pv = (unsigned)__shfl_xor((int)v, 1);       // partner col
    if (!(lr & 1)){
      unsigned pack = (v & 0xFFFFu) | (pv << 16);        // cols (j, j+1)
      *(unsigned*)(hout + (size_t)brow * HID + j) = pack;
    }
  }
}

// ---------------------------------------------- ablation probes (round-6 loop)
// MODE 1 = work only (stage + MFMA + epilogue, NO barrier) -> scratch rings.
// MODE 2 = barrier only (round-6 flag barrier, NO work).
// Both write scratch only; launched after real outputs are produced.
template<int MODE>
__global__ void __launch_bounds__(256, 1)
k_probe(const unsigned short* __restrict__ Whh0bf,
        const unsigned short* __restrict__ Wcat1bf,
        const float* __restrict__ embg, const int* __restrict__ text,
        const float* __restrict__ b1sum,
        unsigned short* h0r, unsigned short* h1r,
        unsigned int* flags, unsigned int* rel){
  const int SLOT = B_ * HID;
  const int bid = blockIdx.x;
  const bool isB = bid >= 128;
  const int gb = isB ? bid - 128 : bid;
  const int tid = threadIdx.x;
  const int w = tid >> 6, l = tid & 63, lr = l & 15, lk = l >> 4;
  const int gw = gb * 4 + w;
  const int m0 = ((gb * 4) >> 5) * 16;
  const int j0 = (gw & 31) * 16;
  const int j  = j0 + lr;

  __shared__ unsigned short hS[16][1048];

  float creg0 = 0.f, creg1 = 0.f, creg2 = 0.f, creg3 = 0.f;
  float xb0 = 0.f, xb1 = 0.f, xb2 = 0.f, xb3 = 0.f;
  if (isB && MODE != 2){
    xb0 = b1sum[j]; xb1 = b1sum[512 + j];
    xb2 = b1sum[1024 + j]; xb3 = b1sum[1536 + j];
  }
  const unsigned short* W = isB ? Wcat1bf : Whh0bf;
  const int wstr = isB ? 1024 : 512;
  const int KS   = isB ? 32 : 16;
  const int nld  = isB ? 8 : 4;

  for (int p = 0; p <= 32; ++p){
    const bool active = isB ? (p >= 1) : (p < 32);
    if (MODE != 2 && active){
      const int t = isB ? (p - 1) : p;
      const unsigned short* hA = h0r + (size_t)p * SLOT;
      const unsigned short* hB = h1r + (size_t)(p - 1) * SLOT;

      for (int i = 0; i < nld; ++i){
        int e = tid + 256 * i;
        int part = (isB ? (e >> 10) : 0);
        int ei = e & 1023;
        int row = ei >> 6, c8 = (ei & 63) * 8;
        const unsigned short* src = part ? hB : hA;
        v4u v = __builtin_nontemporal_load(
            (const v4u*)(src + (size_t)(m0 + row) * HID + c8));
        *(v4u*)&hS[row][part * 512 + c8] = v;
      }
      __syncthreads();

      v4f acc0 = {0,0,0,0}, acc1 = {0,0,0,0}, acc2 = {0,0,0,0}, acc3 = {0,0,0,0};
#pragma unroll 4
      for (int ks = 0; ks < KS; ++ks){
        const int kb = ks * 32 + lk * 8;
        v8bf a  = *(const v8bf*)&hS[lr][kb];
        v8bf b0 = ld8(W + (size_t)(0 * HID + j0 + lr) * wstr + kb);
        v8bf b1 = ld8(W + (size_t)(1 * HID + j0 + lr) * wstr + kb);
        v8bf b2 = ld8(W + (size_t)(2 * HID + j0 + lr) * wstr + kb);
        v8bf b3 = ld8(W + (size_t)(3 * HID + j0 + lr) * wstr + kb);
        acc0 = __builtin_amdgcn_mfma_f32_16x16x32_bf16(a, b0, acc0, 0, 0, 0);
        acc1 = __builtin_amdgcn_mfma_f32_16x16x32_bf16(a, b1, acc1, 0, 0, 0);
        acc2 = __builtin_amdgcn_mfma_f32_16x16x32_bf16(a, b2, acc2, 0, 0, 0);
        acc3 = __builtin_amdgcn_mfma_f32_16x16x32_bf16(a, b3, acc3, 0, 0, 0);
      }

      unsigned short* hout = isB ? (h1r + (size_t)p * SLOT)
                                 : (h0r + (size_t)(p + 1) * SLOT);
#pragma unroll
      for (int r = 0; r < 4; ++r){
        const int brow = m0 + lk * 4 + r;
        float xi, xf, xg, xo;
        if (!isB){
          const float* eg = embg + (size_t)text[brow * T_ + t] * G4 + j;
          xi = eg[0]; xf = eg[512]; xg = eg[1024]; xo = eg[1536];
        } else {
          xi = xb0; xf = xb1; xg = xb2; xo = xb3;
        }
        float ig = acc0[r] + xi, fg = acc1[r] + xf;
        float gg = acc2[r] + xg, og = acc3[r] + xo;
        float cprev = (r == 0) ? creg0 : (r == 1) ? creg1 : (r == 2) ? creg2 : creg3;
        float cn = sigm(fg) * cprev + sigm(ig) * tanh_f(gg);
        if (r == 0) creg0 = cn; else if (r == 1) creg1 = cn;
        else if (r == 2) creg2 = cn; else creg3 = cn;
        float hn = sigm(og) * tanh_f(cn);
        unsigned v = f2bf(hn);
        unsigned pv = (unsigned)__shfl_xor((int)v, 1);
        if (!(lr & 1)){
          unsigned pack = (v & 0xFFFFu) | (pv << 16);
          __hip_atomic_store((unsigned*)(hout + (size_t)brow * HID + j), pack,
                             __ATOMIC_RELAXED, __HIP_MEMORY_SCOPE_AGENT);
        }
      }
    }
    if (MODE != 1 && p != 32){
      const unsigned tgt = (unsigned)(p + 1);
      __syncthreads();
      if (tid == 0)
        __hip_atomic_store(&flags[bid * 16], tgt,
                           __ATOMIC_RELAXED, __HIP_MEMORY_SCOPE_AGENT);
      if (bid == 0){
        while (__hip_atomic_load(&flags[tid * 16],
                                 __ATOMIC_RELAXED, __HIP_MEMORY_SCOPE_AGENT) < tgt)
          __builtin_amdgcn_s_sleep(2);
        __syncthreads();
        if (tid < 8)
          __hip_atomic_store(&rel[tid * 16], tgt,
                             __ATOMIC_RELAXED, __HIP_MEMORY_SCOPE_AGENT);
      } else {
        if (tid == 0){
          while (__hip_atomic_load(&rel[(bid & 7) * 16],
                                   __ATOMIC_RELAXED, __HIP_MEMORY_SCOPE_AGENT) < tgt)
            __builtin_amdgcn_s_sleep(2);
        }
        __syncthreads();
      }
      asm volatile("" ::: "memory");
    }
    if (MODE == 1 && p != 32) __syncthreads();
  }
}

// ----------------------------------------------------- batched attention ----
__global__ void __launch_bounds__(256)
k_attn1(const unsigned short* __restrict__ fT, const unsigned short* __restrict__ h1r,
        float* __restrict__ d_out){
  int b = blockIdx.x, tid = threadIdx.x, w = tid >> 6, l = tid & 63;
  int lr = l & 15, lk = l >> 4;
  const unsigned short* fb = fT + (size_t)b * L_ * HID;
  v4f acc[2][4] = {};
  for (int ks = 0; ks < 16; ++ks){
    int kb = ks * 32 + lk * 8;
    v8bf a0 = ld8(h1r + ((size_t)(lr + 1)  * B_ + b) * HID + kb);   // t = lr
    v8bf a1 = ld8(h1r + ((size_t)(lr + 17) * B_ + b) * HID + kb);   // t = 16+lr
#pragma unroll
    for (int fn = 0; fn < 4; ++fn){
      v8bf bf = ld8(fb + (size_t)(w * 64 + fn * 16 + lr) * HID + kb);
      acc[0][fn] = __builtin_amdgcn_mfma_f32_16x16x32_bf16(a0, bf, acc[0][fn], 0, 0, 0);
      acc[1][fn] = __builtin_amdgcn_mfma_f32_16x16x32_bf16(a1, bf, acc[1][fn], 0, 0, 0);
    }
  }
#pragma unroll
  for (int fm = 0; fm < 2; ++fm)
#pragma unroll
    for (int fn = 0; fn < 4; ++fn)
#pragma unroll
      for (int r = 0; r < 4; ++r){
        int tt = fm * 16 + lk * 4 + r;
        int li = w * 64 + fn * 16 + lr;
        d_out[MASK_OFF + ((size_t)b * T_ + tt) * L_ + li] = sigm(acc[fm][fn][r]);
      }
}

__global__ void __launch_bounds__(512)
k_attn2(const unsigned short* __restrict__ fT, const float* __restrict__ d_out_ro,
        float* __restrict__ d_out, unsigned short* __restrict__ ctxbf){
  int b = blockIdx.x, tid = threadIdx.x, w = tid >> 6, l = tid & 63;
  __shared__ float aS[T_][L_];
  const float* ab = d_out_ro + MASK_OFF + (size_t)b * T_ * L_;
  for (int i = tid * 4; i < T_ * L_; i += 512 * 4){
    float4 v = *(const float4*)(ab + i);
    int tt = i >> 8, ll = i & 255;
    aS[tt][ll+0] = v.x; aS[tt][ll+1] = v.y; aS[tt][ll+2] = v.z; aS[tt][ll+3] = v.w;
  }
  __syncthreads();
  float acc[4][8] = {};
  const unsigned short* fb = fT + (size_t)b * L_ * HID + l * 8;
  for (int li = 0; li < L_; ++li){
    ushort4 u0 = *(const ushort4*)(fb + (size_t)li * HID);
    ushort4 u1 = *(const ushort4*)(fb + (size_t)li * HID + 4);
    float f[8] = {bf2f(u0.x), bf2f(u0.y), bf2f(u0.z), bf2f(u0.w),
                  bf2f(u1.x), bf2f(u1.y), bf2f(u1.z), bf2f(u1.w)};
#pragma unroll
    for (int tt = 0; tt < 4; ++tt){
      float a = aS[w * 4 + tt][li];
#pragma unroll
      for (int k = 0; k < 8; ++k) acc[tt][k] += a * f[k];
    }
  }
#pragma unroll
  for (int tt = 0; tt < 4; ++tt)
#pragma unroll
    for (int k = 0; k < 8; ++k){
      size_t o = ((size_t)b * T_ + w * 4 + tt) * HID + l * 8 + k;
      d_out[OH_OFF + o] = acc[tt][k];
      ctxbf[o] = f2bf(acc[tt][k]);
    }
}

// ------------------------------------------------------------------ final ---
__global__ void __launch_bounds__(256)
k_gen_m(const unsigned short* __restrict__ ctxbf, const unsigned short* __restrict__ genWbf,
        const float* __restrict__ genb, float* __restrict__ g){
  int m0 = blockIdx.x * 64 + (threadIdx.x >> 6) * 16;
  int j0 = blockIdx.y * 16;
  int l = threadIdx.x & 63, lr = l & 15, lk = l >> 4;
  int n = j0 + lr, nr = min(n, NC - 1);
  v4f acc = {0,0,0,0};
  for (int ks = 0; ks < 16; ++ks){
    int kb = ks * 32 + lk * 8;
    v8bf a  = ld8(ctxbf + (size_t)(m0 + lr) * HID + kb);
    v8bf bf = ld8(genWbf + (size_t)nr * HID + kb);
    acc = __builtin_amdgcn_mfma_f32_16x16x32_bf16(a, bf, acc, 0, 0, 0);
  }
  if (n < NC){
    float bb = genb[n];
#pragma unroll
    for (int r = 0; r < 4; ++r)
      g[(size_t)(m0 + lk * 4 + r) * NC + n] = acc[r] + bb;
  }
}

// --------------------------------------------------------------- fallbacks --
__global__ void __launch_bounds__(256)
k_attn_direct(const float* __restrict__ orig, const unsigned short* __restrict__ h1b,
              float* __restrict__ d_out, int t){
  int b = blockIdx.x, tid = threadIdx.x;
  __shared__ float h1s[HID];
  __shared__ float as[L_];
  h1s[tid]       = bf2f(h1b[(size_t)b * HID + tid]);
  h1s[256 + tid] = bf2f(h1b[(size_t)b * HID + 256 + tid]);
  __syncthreads();
  const float* fb = orig + (size_t)b * HID * L_;
  float dot = 0.f;
  for (int ch = 0; ch < HID; ++ch) dot += h1s[ch] * fb[(size_t)ch * L_ + tid];
  float a = sigm(dot);
  as[tid] = a;
  d_out[MASK_OFF + ((size_t)b * T_ + t) * L_ + tid] = a;
  __syncthreads();
  for (int cc = 0; cc < 2; ++cc){
    int ch = tid + cc * 256;
    float s = 0.f;
    for (int ll = 0; ll < L_; ++ll) s += as[ll] * fb[(size_t)ch * L_ + ll];
    d_out[OH_OFF + ((size_t)b * T_ + t) * HID + ch] = s;
  }
}

__global__ void k_gen_v(const float* __restrict__ ctx, const float* __restrict__ genW,
                        const float* __restrict__ genb, float* __restrict__ g){
  int o = blockIdx.x * 256 + threadIdx.x;
  if (o >= B_ * T_ * NC) return;
  int m = o / NC, n = o - m * NC;
  const float4* a = (const float4*)(ctx + (size_t)m * HID);
  const float4* wv = (const float4*)(genW + (size_t)n * HID);
  float s = genb[n];
  for (int k = 0; k < HID / 4; ++k){
    float4 av = a[k], w = wv[k];
    s += av.x * w.x + av.y * w.y + av.z * w.z + av.w * w.w;
  }
  g[o] = s;
}

// -----------------------------------------------------------------------------
extern "C" void kernel_launch(void* const* d_in, const int* in_sizes, int n_in,
                              void* d_out, int out_size, void* d_ws, size_t ws_size,
                              hipStream_t stream){
  const float* orig = (const float*)d_in[0];
  const int*   text = (const int*)  d_in[1];
  const float* embW = (const float*)d_in[2];
  const float* embb = (const float*)d_in[3];
  const float* Wih0 = (const float*)d_in[4];
  const float* Whh0 = (const float*)d_in[5];
  const float* bih0 = (const float*)d_in[6];
  const float* bhh0 = (const float*)d_in[7];
  const float* Wih1 = (const float*)d_in[8];
  const float* Whh1 = (const float*)d_in[9];
  const float* bih1 = (const float*)d_in[10];
  const float* bhh1 = (const float*)d_in[11];
  const float* genW = (const float*)d_in[12];
  const float* genb = (const float*)d_in[13];
  float* out = (float*)d_out;

  const size_t SLOTB = (size_t)B_ * HID * 2;          // 256 KB

  char* p = (char*)d_ws;
  float* embg  = (float*)p;           p += (size_t)NC * G4 * 4;
  float* b1sum = (float*)p;           p += (size_t)G4 * 4;
  // ---- zero-init region ----
  unsigned short* hx0 = (unsigned short*)p;    p += 2 * SLOTB;      // h0 ping-pong
  float* c0 = (float*)p;                       p += (size_t)B_ * HID * 4;
  float* c1 = (float*)p;                       p += (size_t)B_ * HID * 4;
  unsigned int* pflags = (unsigned int*)p;     p += 256 * 64;
  unsigned int* prel   = (unsigned int*)p;     p += 8 * 64;
  size_t zbytes = (size_t)((char*)p - (char*)hx0);
  // ---- end zero region ----
  unsigned short* Whh0bf  = (unsigned short*)p; p += (size_t)G4 * 512 * 2;
  unsigned short* Wcat1bf = (unsigned short*)p; p += (size_t)G4 * 1024 * 2;
  unsigned short* Wih0bf  = (unsigned short*)p; p += (size_t)G4 * 512 * 2;
  unsigned short* embXbf  = (unsigned short*)p; p += (size_t)NC * HID * 2;
  unsigned short* genWbf  = (unsigned short*)p; p += (size_t)NC * HID * 2;
  unsigned short* h1r = (unsigned short*)p;    p += 33 * SLOTB;     // h1 ring (8.25MB)
  unsigned short* ctxbf = (unsigned short*)p;  p += (size_t)B_ * T_ * HID * 2;  // 8MB
  unsigned short* ph0r = (unsigned short*)p;   p += 34 * SLOTB;     // probe scratch
  unsigned short* ph1r = (unsigned short*)p;   p += 34 * SLOTB;     // probe scratch
  unsigned short* fmapT = (unsigned short*)p;  p += (size_t)B_ * L_ * HID * 2;  // 64MB
  bool big = ws_size >= (size_t)(p - (char*)d_ws);

  hipMemsetAsync(hx0, 0, zbytes, stream);
  hipMemsetAsync(h1r, 0, SLOTB, stream);              // h1(0) = zeros

  k_wconv<<<(G4 * HID + 255) / 256, 256, 0, stream>>>(Whh0, Wih1, Whh1, Wih0,
                                                      Whh0bf, Wcat1bf, Wih0bf);
  k_small<<<(NC * HID + 255) / 256, 256, 0, stream>>>(embW, embb, genW, bih1, bhh1,
                                                      embXbf, genWbf, b1sum);
  k_embg_m<<<dim3(7, G4 / 16), 64, 0, stream>>>(embXbf, Wih0bf, bih0, bhh0, embg);
  if (big) k_fmapT<<<dim3(L_ / 32, HID / 32, B_), dim3(32, 8), 0, stream>>>(orig, fmapT);

  // ---- the recurrence: 33 fused pipelined launches, no in-kernel sync ----
  for (int pp = 0; pp <= 32; ++pp)
    k_step<<<256, 256, 0, stream>>>(Whh0bf, Wcat1bf, embg, text, b1sum,
                                    hx0, h1r, c0, c1, pp);

  if (big){
    k_attn1<<<B_, 256, 0, stream>>>(fmapT, h1r, out);
    k_attn2<<<B_, 512, 0, stream>>>(fmapT, (const float*)out, out, ctxbf);
    k_gen_m<<<dim3(B_ * T_ / 64, 7), 256, 0, stream>>>(ctxbf, genWbf, genb, out);

    // ---- ablation probes (scratch-only; timings read from rocprof) ----
    {
      const unsigned short* a0 = Whh0bf; const unsigned short* a1 = Wcat1bf;
      const float* a2 = embg; const int* a3 = text; const float* a4 = b1sum;
      unsigned short* a5 = ph0r; unsigned short* a6 = ph1r;
      unsigned int* a7 = pflags; unsigned int* a8 = prel;
      void* args[] = {&a0, &a1, &a2, &a3, &a4, &a5, &a6, &a7, &a8};
      hipLaunchCooperativeKernel((const void*)k_probe<2>, dim3(256), dim3(256),
                                 args, 0, stream);   // barrier-only
      hipLaunchCooperativeKernel((const void*)k_probe<1>, dim3(256), dim3(256),
                                 args, 0, stream);   // work-only
    }
  } else {
    for (int t = 0; t < T_; ++t)
      k_attn_direct<<<B_, 256, 0, stream>>>(orig, h1r + (size_t)(t + 1) * B_ * HID,
                                            out, t);
    k_gen_v<<<(B_ * T_ * NC + 255) / 256, 256, 0, stream>>>(out + OH_OFF, genW, genb, out);
  }
}

// Round 9
// 823.541 us; speedup vs baseline: 4164.1704x; 1.7660x over previous
//
#include <hip/hip_runtime.h>

#define B_   256
#define HID  512
#define T_   32
#define L_   256
#define NC   97
#define G4   2048

// d_out layout (f32): g [256,32,97] | output_hiddens [256,32,512] | masks [256,32,8,32]
#define OH_OFF   794624
#define MASK_OFF 4988928

typedef __bf16 v8bf __attribute__((ext_vector_type(8)));
typedef float  v4f  __attribute__((ext_vector_type(4)));
typedef unsigned int v4u __attribute__((ext_vector_type(4)));

__device__ __forceinline__ unsigned short f2bf(float x){
  unsigned u = __float_as_uint(x);
  u += 0x7FFFu + ((u >> 16) & 1u);          // round-to-nearest-even
  return (unsigned short)(u >> 16);
}
__device__ __forceinline__ float bf2f(unsigned short h){
  return __uint_as_float(((unsigned)h) << 16);
}
__device__ __forceinline__ float sigm(float x){ return 1.f / (1.f + __expf(-x)); }
__device__ __forceinline__ float tanh_f(float x){
  float e = __expf(2.f * x);
  return 1.f - 2.f / (e + 1.f);             // safe at +/-inf
}
__device__ __forceinline__ v8bf ld8(const unsigned short* p){
  return *reinterpret_cast<const v8bf*>(p);
}

// ---------------------------------------------------------------- one-time --
__global__ void k_wconv(const float* __restrict__ Whh0, const float* __restrict__ Wih1,
                        const float* __restrict__ Whh1, const float* __restrict__ Wih0,
                        unsigned short* __restrict__ Whh0bf, unsigned short* __restrict__ Wcat1bf,
                        unsigned short* __restrict__ Wih0bf){
  int i = blockIdx.x * 256 + threadIdx.x;
  if (i >= G4 * HID) return;
  Whh0bf[i] = f2bf(Whh0[i]);
  Wih0bf[i] = f2bf(Wih0[i]);
  int n = i >> 9, k = i & 511;
  Wcat1bf[(size_t)n * 1024 + k]       = f2bf(Wih1[i]);
  Wcat1bf[(size_t)n * 1024 + 512 + k] = f2bf(Whh1[i]);
}

__global__ void k_small(const float* __restrict__ embW, const float* __restrict__ embb,
                        const float* __restrict__ genW, const float* __restrict__ bih1,
                        const float* __restrict__ bhh1,
                        unsigned short* __restrict__ embXbf, unsigned short* __restrict__ genWbf,
                        float* __restrict__ b1sum){
  int i = blockIdx.x * 256 + threadIdx.x;
  if (i < NC * HID){
    int c = i >> 9, h = i & 511;
    embXbf[i] = f2bf(embW[h * NC + c] + embb[h]);
    genWbf[i] = f2bf(genW[i]);
  }
  if (i < G4) b1sum[i] = bih1[i] + bhh1[i];
}

// emb_gates[c][n] (MFMA, M=97 N=2048 K=512)
__global__ void __launch_bounds__(64)
k_embg_m(const unsigned short* __restrict__ embXbf, const unsigned short* __restrict__ Wih0bf,
         const float* __restrict__ bih0, const float* __restrict__ bhh0,
         float* __restrict__ embg){
  int m0 = blockIdx.x * 16, j0 = blockIdx.y * 16;
  int l = threadIdx.x, lr = l & 15, lk = l >> 4;
  int ar = min(m0 + lr, NC - 1);
  v4f acc = {0,0,0,0};
  for (int ks = 0; ks < 16; ++ks){
    int kb = ks * 32 + lk * 8;
    v8bf a  = ld8(embXbf + (size_t)ar * HID + kb);
    v8bf bf = ld8(Wih0bf + (size_t)(j0 + lr) * HID + kb);
    acc = __builtin_amdgcn_mfma_f32_16x16x32_bf16(a, bf, acc, 0, 0, 0);
  }
  int n = j0 + lr;
  float bb = bih0[n] + bhh0[n];
#pragma unroll
  for (int r = 0; r < 4; ++r){
    int c = m0 + lk * 4 + r;
    if (c < NC) embg[(size_t)c * G4 + n] = acc[r] + bb;
  }
}

// origin[b][c][l] f32 -> fmapT[b][l][c] bf16
__global__ void k_fmapT(const float* __restrict__ orig, unsigned short* __restrict__ fT){
  __shared__ float tile[32][33];
  int b = blockIdx.z, c0 = blockIdx.y * 32, l0 = blockIdx.x * 32;
  const float* src = orig + ((size_t)b * HID + c0) * L_ + l0;
  for (int i = 0; i < 32; i += 8)
    tile[threadIdx.y + i][threadIdx.x] = src[(threadIdx.y + i) * L_ + threadIdx.x];
  __syncthreads();
  unsigned short* dst = fT + ((size_t)b * L_ + l0) * HID + c0;
  for (int i = 0; i < 32; i += 8)
    dst[(threadIdx.y + i) * HID + threadIdx.x] = f2bf(tile[threadIdx.x][threadIdx.y + i]);
}

// ----------------------------------------------- fused per-step LSTM launch --
// Launched 33x (p = 0..32). Blocks 0..127: LSTM0 step p (skip if p==32).
// Blocks 128..255: LSTM1 step p-1 (skip if p==0). A and B are independent
// within a launch; all producer->consumer edges cross a kernel boundary, so
// plain cached loads/stores are coherent (h lands in MALL; next launch's
// invalidated L2 refetches from L3 -- NOT HBM; never use nt here).
// No LDS staging: each wave loads its own A-fragments directly (h is 256KB,
// L2/L3-resident; 4x wave redundancy is cheaper than a stage+syncthreads).
__global__ void __launch_bounds__(256)
k_step(const unsigned short* __restrict__ Whh0bf,
       const unsigned short* __restrict__ Wcat1bf,
       const float* __restrict__ embg, const int* __restrict__ text,
       const float* __restrict__ b1sum,
       unsigned short* __restrict__ hx0, unsigned short* __restrict__ h1r,
       float* __restrict__ c0, float* __restrict__ c1, int p){
  const int SLOT = B_ * HID;
  const int bid = blockIdx.x;
  const bool isB = bid >= 128;
  if (isB ? (p < 1) : (p >= 32)) return;
  const int gb = bid & 127;
  const int tid = threadIdx.x;
  const int w = tid >> 6, l = tid & 63, lr = l & 15, lk = l >> 4;
  const int m0 = (gb >> 3) * 16;
  const int jw = (gb & 7) * 64 + w * 16;
  const int j  = jw + lr;
  const int t  = isB ? (p - 1) : p;

  const unsigned short* hA = hx0 + (size_t)(p & 1) * SLOT;              // h0(p)
  const unsigned short* hB = h1r + (size_t)(isB ? (p - 1) : 0) * SLOT;  // h1(p-1)
  const unsigned short* W = isB ? Wcat1bf : Whh0bf;
  const int wstr = isB ? 1024 : 512;
  const int KS   = isB ? 32 : 16;

  v4f acc0 = {0,0,0,0}, acc1 = {0,0,0,0}, acc2 = {0,0,0,0}, acc3 = {0,0,0,0};
#pragma unroll 4
  for (int ks = 0; ks < KS; ++ks){
    const int kb = ks * 32 + lk * 8;
    const unsigned short* Ap = (isB && ks >= 16) ? hB : hA;
    const int ka = (isB && ks >= 16) ? (kb - 512) : kb;
    v8bf a  = ld8(Ap + (size_t)(m0 + lr) * HID + ka);
    v8bf b0 = ld8(W + (size_t)(0 * HID + j) * wstr + kb);
    v8bf b1 = ld8(W + (size_t)(1 * HID + j) * wstr + kb);
    v8bf b2 = ld8(W + (size_t)(2 * HID + j) * wstr + kb);
    v8bf b3 = ld8(W + (size_t)(3 * HID + j) * wstr + kb);
    acc0 = __builtin_amdgcn_mfma_f32_16x16x32_bf16(a, b0, acc0, 0, 0, 0);
    acc1 = __builtin_amdgcn_mfma_f32_16x16x32_bf16(a, b1, acc1, 0, 0, 0);
    acc2 = __builtin_amdgcn_mfma_f32_16x16x32_bf16(a, b2, acc2, 0, 0, 0);
    acc3 = __builtin_amdgcn_mfma_f32_16x16x32_bf16(a, b3, acc3, 0, 0, 0);
  }

  float xb0 = 0.f, xb1 = 0.f, xb2 = 0.f, xb3 = 0.f;
  if (isB){
    xb0 = b1sum[j]; xb1 = b1sum[512 + j];
    xb2 = b1sum[1024 + j]; xb3 = b1sum[1536 + j];
  }
  float* cst = isB ? c1 : c0;
  unsigned short* hout = isB ? (h1r + (size_t)p * SLOT)             // h1(p)
                             : (hx0 + (size_t)((p + 1) & 1) * SLOT);// h0(p+1)
#pragma unroll
  for (int r = 0; r < 4; ++r){
    const int brow = m0 + lk * 4 + r;
    float xi, xf, xg, xo;
    if (!isB){
      const float* eg = embg + (size_t)text[brow * T_ + t] * G4 + j;
      xi = eg[0]; xf = eg[512]; xg = eg[1024]; xo = eg[1536];
    } else {
      xi = xb0; xf = xb1; xg = xb2; xo = xb3;
    }
    float ig = acc0[r] + xi, fg = acc1[r] + xf;
    float gg = acc2[r] + xg, og = acc3[r] + xo;
    size_t ci = (size_t)brow * HID + j;
    float cn = sigm(fg) * cst[ci] + sigm(ig) * tanh_f(gg);
    cst[ci] = cn;
    float hn = sigm(og) * tanh_f(cn);
    unsigned v = f2bf(hn);
    unsigned pv = (unsigned)__shfl_xor((int)v, 1);       // partner col
    if (!(lr & 1)){
      unsigned pack = (v & 0xFFFFu) | (pv << 16);        // cols (j, j+1)
      *(unsigned*)(hout + (size_t)brow * HID + j) = pack;
    }
  }
}

// ----------------------------------------------------- batched attention ----
__global__ void __launch_bounds__(256)
k_attn1(const unsigned short* __restrict__ fT, const unsigned short* __restrict__ h1r,
        float* __restrict__ d_out){
  int b = blockIdx.x, tid = threadIdx.x, w = tid >> 6, l = tid & 63;
  int lr = l & 15, lk = l >> 4;
  const unsigned short* fb = fT + (size_t)b * L_ * HID;
  v4f acc[2][4] = {};
  for (int ks = 0; ks < 16; ++ks){
    int kb = ks * 32 + lk * 8;
    v8bf a0 = ld8(h1r + ((size_t)(lr + 1)  * B_ + b) * HID + kb);   // t = lr
    v8bf a1 = ld8(h1r + ((size_t)(lr + 17) * B_ + b) * HID + kb);   // t = 16+lr
#pragma unroll
    for (int fn = 0; fn < 4; ++fn){
      v8bf bf = ld8(fb + (size_t)(w * 64 + fn * 16 + lr) * HID + kb);
      acc[0][fn] = __builtin_amdgcn_mfma_f32_16x16x32_bf16(a0, bf, acc[0][fn], 0, 0, 0);
      acc[1][fn] = __builtin_amdgcn_mfma_f32_16x16x32_bf16(a1, bf, acc[1][fn], 0, 0, 0);
    }
  }
#pragma unroll
  for (int fm = 0; fm < 2; ++fm)
#pragma unroll
    for (int fn = 0; fn < 4; ++fn)
#pragma unroll
      for (int r = 0; r < 4; ++r){
        int tt = fm * 16 + lk * 4 + r;
        int li = w * 64 + fn * 16 + lr;
        d_out[MASK_OFF + ((size_t)b * T_ + tt) * L_ + li] = sigm(acc[fm][fn][r]);
      }
}

__global__ void __launch_bounds__(512)
k_attn2(const unsigned short* __restrict__ fT, const float* __restrict__ d_out_ro,
        float* __restrict__ d_out, unsigned short* __restrict__ ctxbf){
  int b = blockIdx.x, tid = threadIdx.x, w = tid >> 6, l = tid & 63;
  __shared__ float aS[T_][L_];
  const float* ab = d_out_ro + MASK_OFF + (size_t)b * T_ * L_;
  for (int i = tid * 4; i < T_ * L_; i += 512 * 4){
    float4 v = *(const float4*)(ab + i);
    int tt = i >> 8, ll = i & 255;
    aS[tt][ll+0] = v.x; aS[tt][ll+1] = v.y; aS[tt][ll+2] = v.z; aS[tt][ll+3] = v.w;
  }
  __syncthreads();
  float acc[4][8] = {};
  const unsigned short* fb = fT + (size_t)b * L_ * HID + l * 8;
  for (int li = 0; li < L_; ++li){
    ushort4 u0 = *(const ushort4*)(fb + (size_t)li * HID);
    ushort4 u1 = *(const ushort4*)(fb + (size_t)li * HID + 4);
    float f[8] = {bf2f(u0.x), bf2f(u0.y), bf2f(u0.z), bf2f(u0.w),
                  bf2f(u1.x), bf2f(u1.y), bf2f(u1.z), bf2f(u1.w)};
#pragma unroll
    for (int tt = 0; tt < 4; ++tt){
      float a = aS[w * 4 + tt][li];
#pragma unroll
      for (int k = 0; k < 8; ++k) acc[tt][k] += a * f[k];
    }
  }
#pragma unroll
  for (int tt = 0; tt < 4; ++tt)
#pragma unroll
    for (int k = 0; k < 8; ++k){
      size_t o = ((size_t)b * T_ + w * 4 + tt) * HID + l * 8 + k;
      d_out[OH_OFF + o] = acc[tt][k];
      ctxbf[o] = f2bf(acc[tt][k]);
    }
}

// ------------------------------------------------------------------ final ---
__global__ void __launch_bounds__(256)
k_gen_m(const unsigned short* __restrict__ ctxbf, const unsigned short* __restrict__ genWbf,
        const float* __restrict__ genb, float* __restrict__ g){
  int m0 = blockIdx.x * 64 + (threadIdx.x >> 6) * 16;
  int j0 = blockIdx.y * 16;
  int l = threadIdx.x & 63, lr = l & 15, lk = l >> 4;
  int n = j0 + lr, nr = min(n, NC - 1);
  v4f acc = {0,0,0,0};
  for (int ks = 0; ks < 16; ++ks){
    int kb = ks * 32 + lk * 8;
    v8bf a  = ld8(ctxbf + (size_t)(m0 + lr) * HID + kb);
    v8bf bf = ld8(genWbf + (size_t)nr * HID + kb);
    acc = __builtin_amdgcn_mfma_f32_16x16x32_bf16(a, bf, acc, 0, 0, 0);
  }
  if (n < NC){
    float bb = genb[n];
#pragma unroll
    for (int r = 0; r < 4; ++r)
      g[(size_t)(m0 + lk * 4 + r) * NC + n] = acc[r] + bb;
  }
}

// --------------------------------------------------------------- fallbacks --
__global__ void __launch_bounds__(256)
k_attn_direct(const float* __restrict__ orig, const unsigned short* __restrict__ h1b,
              float* __restrict__ d_out, int t){
  int b = blockIdx.x, tid = threadIdx.x;
  __shared__ float h1s[HID];
  __shared__ float as[L_];
  h1s[tid]       = bf2f(h1b[(size_t)b * HID + tid]);
  h1s[256 + tid] = bf2f(h1b[(size_t)b * HID + 256 + tid]);
  __syncthreads();
  const float* fb = orig + (size_t)b * HID * L_;
  float dot = 0.f;
  for (int ch = 0; ch < HID; ++ch) dot += h1s[ch] * fb[(size_t)ch * L_ + tid];
  float a = sigm(dot);
  as[tid] = a;
  d_out[MASK_OFF + ((size_t)b * T_ + t) * L_ + tid] = a;
  __syncthreads();
  for (int cc = 0; cc < 2; ++cc){
    int ch = tid + cc * 256;
    float s = 0.f;
    for (int ll = 0; ll < L_; ++ll) s += as[ll] * fb[(size_t)ch * L_ + ll];
    d_out[OH_OFF + ((size_t)b * T_ + t) * HID + ch] = s;
  }
}

__global__ void k_gen_v(const float* __restrict__ ctx, const float* __restrict__ genW,
                        const float* __restrict__ genb, float* __restrict__ g){
  int o = blockIdx.x * 256 + threadIdx.x;
  if (o >= B_ * T_ * NC) return;
  int m = o / NC, n = o - m * NC;
  const float4* a = (const float4*)(ctx + (size_t)m * HID);
  const float4* wv = (const float4*)(genW + (size_t)n * HID);
  float s = genb[n];
  for (int k = 0; k < HID / 4; ++k){
    float4 av = a[k], w = wv[k];
    s += av.x * w.x + av.y * w.y + av.z * w.z + av.w * w.w;
  }
  g[o] = s;
}

// -----------------------------------------------------------------------------
extern "C" void kernel_launch(void* const* d_in, const int* in_sizes, int n_in,
                              void* d_out, int out_size, void* d_ws, size_t ws_size,
                              hipStream_t stream){
  const float* orig = (const float*)d_in[0];
  const int*   text = (const int*)  d_in[1];
  const float* embW = (const float*)d_in[2];
  const float* embb = (const float*)d_in[3];
  const float* Wih0 = (const float*)d_in[4];
  const float* Whh0 = (const float*)d_in[5];
  const float* bih0 = (const float*)d_in[6];
  const float* bhh0 = (const float*)d_in[7];
  const float* Wih1 = (const float*)d_in[8];
  const float* Whh1 = (const float*)d_in[9];
  const float* bih1 = (const float*)d_in[10];
  const float* bhh1 = (const float*)d_in[11];
  const float* genW = (const float*)d_in[12];
  const float* genb = (const float*)d_in[13];
  float* out = (float*)d_out;

  const size_t SLOTB = (size_t)B_ * HID * 2;          // 256 KB

  char* p = (char*)d_ws;
  float* embg  = (float*)p;           p += (size_t)NC * G4 * 4;
  float* b1sum = (float*)p;           p += (size_t)G4 * 4;
  // ---- zero-init region ----
  unsigned short* hx0 = (unsigned short*)p;    p += 2 * SLOTB;      // h0 ping-pong
  float* c0 = (float*)p;                       p += (size_t)B_ * HID * 4;
  float* c1 = (float*)p;                       p += (size_t)B_ * HID * 4;
  size_t zbytes = (size_t)((char*)p - (char*)hx0);
  // ---- end zero region ----
  unsigned short* Whh0bf  = (unsigned short*)p; p += (size_t)G4 * 512 * 2;
  unsigned short* Wcat1bf = (unsigned short*)p; p += (size_t)G4 * 1024 * 2;
  unsigned short* Wih0bf  = (unsigned short*)p; p += (size_t)G4 * 512 * 2;
  unsigned short* embXbf  = (unsigned short*)p; p += (size_t)NC * HID * 2;
  unsigned short* genWbf  = (unsigned short*)p; p += (size_t)NC * HID * 2;
  unsigned short* h1r = (unsigned short*)p;    p += 33 * SLOTB;     // h1 ring (8.25MB)
  unsigned short* ctxbf = (unsigned short*)p;  p += (size_t)B_ * T_ * HID * 2;  // 8MB
  unsigned short* fmapT = (unsigned short*)p;  p += (size_t)B_ * L_ * HID * 2;  // 64MB
  bool big = ws_size >= (size_t)(p - (char*)d_ws);

  hipMemsetAsync(hx0, 0, zbytes, stream);
  hipMemsetAsync(h1r, 0, SLOTB, stream);              // h1(0) = zeros

  k_wconv<<<(G4 * HID + 255) / 256, 256, 0, stream>>>(Whh0, Wih1, Whh1, Wih0,
                                                      Whh0bf, Wcat1bf, Wih0bf);
  k_small<<<(NC * HID + 255) / 256, 256, 0, stream>>>(embW, embb, genW, bih1, bhh1,
                                                      embXbf, genWbf, b1sum);
  k_embg_m<<<dim3(7, G4 / 16), 64, 0, stream>>>(embXbf, Wih0bf, bih0, bhh0, embg);
  if (big) k_fmapT<<<dim3(L_ / 32, HID / 32, B_), dim3(32, 8), 0, stream>>>(orig, fmapT);

  // ---- the recurrence: 33 fused pipelined launches, no in-kernel sync ----
  for (int pp = 0; pp <= 32; ++pp)
    k_step<<<256, 256, 0, stream>>>(Whh0bf, Wcat1bf, embg, text, b1sum,
                                    hx0, h1r, c0, c1, pp);

  if (big){
    k_attn1<<<B_, 256, 0, stream>>>(fmapT, h1r, out);
    k_attn2<<<B_, 512, 0, stream>>>(fmapT, (const float*)out, out, ctxbf);
    k_gen_m<<<dim3(B_ * T_ / 64, 7), 256, 0, stream>>>(ctxbf, genWbf, genb, out);
  } else {
    for (int t = 0; t < T_; ++t)
      k_attn_direct<<<B_, 256, 0, stream>>>(orig, h1r + (size_t)(t + 1) * B_ * HID,
                                            out, t);
    k_gen_v<<<(B_ * T_ * NC + 255) / 256, 256, 0, stream>>>(out + OH_OFF, genW, genb, out);
  }
}

// Round 10
// 758.541 us; speedup vs baseline: 4521.0010x; 1.0857x over previous
//
#include <hip/hip_runtime.h>

#define B_   256
#define HID  512
#define T_   32
#define L_   256
#define NC   97
#define G4   2048

// d_out layout (f32): g [256,32,97] | output_hiddens [256,32,512] | masks [256,32,8,32]
#define OH_OFF   794624
#define MASK_OFF 4988928

typedef __bf16 v8bf __attribute__((ext_vector_type(8)));
typedef float  v4f  __attribute__((ext_vector_type(4)));
typedef unsigned int v4u __attribute__((ext_vector_type(4)));

__device__ __forceinline__ unsigned short f2bf(float x){
  unsigned u = __float_as_uint(x);
  u += 0x7FFFu + ((u >> 16) & 1u);          // round-to-nearest-even
  return (unsigned short)(u >> 16);
}
__device__ __forceinline__ float bf2f(unsigned short h){
  return __uint_as_float(((unsigned)h) << 16);
}
__device__ __forceinline__ float sigm(float x){ return 1.f / (1.f + __expf(-x)); }
__device__ __forceinline__ float tanh_f(float x){
  float e = __expf(2.f * x);
  return 1.f - 2.f / (e + 1.f);             // safe at +/-inf
}
__device__ __forceinline__ v8bf ld8(const unsigned short* p){
  return *reinterpret_cast<const v8bf*>(p);
}

// ---------------------------------------------------------------- one-time --
__global__ void k_wconv(const float* __restrict__ Whh0, const float* __restrict__ Wih1,
                        const float* __restrict__ Whh1, const float* __restrict__ Wih0,
                        unsigned short* __restrict__ Whh0bf, unsigned short* __restrict__ Wcat1bf,
                        unsigned short* __restrict__ Wih0bf){
  int i = blockIdx.x * 256 + threadIdx.x;
  if (i >= G4 * HID) return;
  Whh0bf[i] = f2bf(Whh0[i]);
  Wih0bf[i] = f2bf(Wih0[i]);
  int n = i >> 9, k = i & 511;
  Wcat1bf[(size_t)n * 1024 + k]       = f2bf(Wih1[i]);
  Wcat1bf[(size_t)n * 1024 + 512 + k] = f2bf(Whh1[i]);
}

__global__ void k_small(const float* __restrict__ embW, const float* __restrict__ embb,
                        const float* __restrict__ genW, const float* __restrict__ bih1,
                        const float* __restrict__ bhh1,
                        unsigned short* __restrict__ embXbf, unsigned short* __restrict__ genWbf,
                        float* __restrict__ b1sum){
  int i = blockIdx.x * 256 + threadIdx.x;
  if (i < NC * HID){
    int c = i >> 9, h = i & 511;
    embXbf[i] = f2bf(embW[h * NC + c] + embb[h]);
    genWbf[i] = f2bf(genW[i]);
  }
  if (i < G4) b1sum[i] = bih1[i] + bhh1[i];
}

// emb_gates[c][n] (MFMA, M=97 N=2048 K=512)
__global__ void __launch_bounds__(64)
k_embg_m(const unsigned short* __restrict__ embXbf, const unsigned short* __restrict__ Wih0bf,
         const float* __restrict__ bih0, const float* __restrict__ bhh0,
         float* __restrict__ embg){
  int m0 = blockIdx.x * 16, j0 = blockIdx.y * 16;
  int l = threadIdx.x, lr = l & 15, lk = l >> 4;
  int ar = min(m0 + lr, NC - 1);
  v4f acc = {0,0,0,0};
  for (int ks = 0; ks < 16; ++ks){
    int kb = ks * 32 + lk * 8;
    v8bf a  = ld8(embXbf + (size_t)ar * HID + kb);
    v8bf bf = ld8(Wih0bf + (size_t)(j0 + lr) * HID + kb);
    acc = __builtin_amdgcn_mfma_f32_16x16x32_bf16(a, bf, acc, 0, 0, 0);
  }
  int n = j0 + lr;
  float bb = bih0[n] + bhh0[n];
#pragma unroll
  for (int r = 0; r < 4; ++r){
    int c = m0 + lk * 4 + r;
    if (c < NC) embg[(size_t)c * G4 + n] = acc[r] + bb;
  }
}

// origin[b][c][l] f32 -> fmapT[b][l][c] bf16
__global__ void k_fmapT(const float* __restrict__ orig, unsigned short* __restrict__ fT){
  __shared__ float tile[32][33];
  int b = blockIdx.z, c0 = blockIdx.y * 32, l0 = blockIdx.x * 32;
  const float* src = orig + ((size_t)b * HID + c0) * L_ + l0;
  for (int i = 0; i < 32; i += 8)
    tile[threadIdx.y + i][threadIdx.x] = src[(threadIdx.y + i) * L_ + threadIdx.x];
  __syncthreads();
  unsigned short* dst = fT + ((size_t)b * L_ + l0) * HID + c0;
  for (int i = 0; i < 32; i += 8)
    dst[(threadIdx.y + i) * HID + threadIdx.x] = f2bf(tile[threadIdx.x][threadIdx.y + i]);
}

// ----------------------------------------------- fused per-step LSTM launch --
// Launched 33x (p = 0..32). Blocks 0..127: LSTM0 step p (skip if p==32).
// Blocks 128..255: LSTM1 step p-1 (skip if p==0). A and B are independent
// within a launch; all producer->consumer edges cross a kernel boundary, so
// plain cached loads/stores are coherent. No atomics, no barriers, no spins.
// LDS staging of the h-tile is ESSENTIAL (round-9 lesson): it pays the L3
// latency ONCE per block via 4-8 pipelined coalesced loads; per-ks direct
// global A-loads put ~700cy of L3 latency inside every MFMA unroll group at
// 1 wave/SIMD occupancy (measured 4x slowdown, round 9).
__global__ void __launch_bounds__(256)
k_step(const unsigned short* __restrict__ Whh0bf,
       const unsigned short* __restrict__ Wcat1bf,
       const float* __restrict__ embg, const int* __restrict__ text,
       const float* __restrict__ b1sum,
       unsigned short* __restrict__ hx0, unsigned short* __restrict__ h1r,
       float* __restrict__ c0, float* __restrict__ c1, int p){
  const int SLOT = B_ * HID;
  const int bid = blockIdx.x;
  const bool isB = bid >= 128;
  if (isB ? (p < 1) : (p >= 32)) return;
  const int gb = bid & 127;
  const int tid = threadIdx.x;
  const int w = tid >> 6, l = tid & 63, lr = l & 15, lk = l >> 4;
  const int m0 = (gb >> 3) * 16;
  const int jw = (gb & 7) * 64 + w * 16;
  const int j  = jw + lr;
  const int t  = isB ? (p - 1) : p;

  __shared__ unsigned short hS[16][1048];    // A: cols 0..511; B: h0|h1 0..1023

  const unsigned short* hA = hx0 + (size_t)(p & 1) * SLOT;              // h0(p)
  const unsigned short* hB = h1r + (size_t)(isB ? (p - 1) : 0) * SLOT;  // h1(p-1)

  if (isB){
#pragma unroll
    for (int i = 0; i < 8; ++i){
      int e = tid + 256 * i;                 // 0..2047 (16B chunks)
      int part = e >> 10, ei = e & 1023;
      int row = ei >> 6, c8 = (ei & 63) * 8;
      const unsigned short* src = (part ? hB : hA) + (size_t)(m0 + row) * HID + c8;
      *(v4u*)&hS[row][part * 512 + c8] = *(const v4u*)src;
    }
  } else {
#pragma unroll
    for (int i = 0; i < 4; ++i){
      int e = tid + 256 * i;                 // 0..1023
      int row = e >> 6, c8 = (e & 63) * 8;
      *(v4u*)&hS[row][c8] = *(const v4u*)(hA + (size_t)(m0 + row) * HID + c8);
    }
  }
  __syncthreads();

  const unsigned short* W = isB ? Wcat1bf : Whh0bf;
  const int wstr = isB ? 1024 : 512;
  const int KS   = isB ? 32 : 16;
  v4f acc0 = {0,0,0,0}, acc1 = {0,0,0,0}, acc2 = {0,0,0,0}, acc3 = {0,0,0,0};
#pragma unroll 4
  for (int ks = 0; ks < KS; ++ks){
    const int kb = ks * 32 + lk * 8;
    v8bf a  = *(const v8bf*)&hS[lr][kb];
    v8bf b0 = ld8(W + (size_t)(0 * HID + jw + lr) * wstr + kb);
    v8bf b1 = ld8(W + (size_t)(1 * HID + jw + lr) * wstr + kb);
    v8bf b2 = ld8(W + (size_t)(2 * HID + jw + lr) * wstr + kb);
    v8bf b3 = ld8(W + (size_t)(3 * HID + jw + lr) * wstr + kb);
    acc0 = __builtin_amdgcn_mfma_f32_16x16x32_bf16(a, b0, acc0, 0, 0, 0);
    acc1 = __builtin_amdgcn_mfma_f32_16x16x32_bf16(a, b1, acc1, 0, 0, 0);
    acc2 = __builtin_amdgcn_mfma_f32_16x16x32_bf16(a, b2, acc2, 0, 0, 0);
    acc3 = __builtin_amdgcn_mfma_f32_16x16x32_bf16(a, b3, acc3, 0, 0, 0);
  }

  float xb0 = 0.f, xb1 = 0.f, xb2 = 0.f, xb3 = 0.f;
  if (isB){
    xb0 = b1sum[j]; xb1 = b1sum[512 + j];
    xb2 = b1sum[1024 + j]; xb3 = b1sum[1536 + j];
  }
  float* cst = isB ? c1 : c0;
  unsigned short* hout = isB ? (h1r + (size_t)p * SLOT)             // h1(p)
                             : (hx0 + (size_t)((p + 1) & 1) * SLOT);// h0(p+1)
#pragma unroll
  for (int r = 0; r < 4; ++r){
    const int brow = m0 + lk * 4 + r;
    float xi, xf, xg, xo;
    if (!isB){
      const float* eg = embg + (size_t)text[brow * T_ + t] * G4 + j;
      xi = eg[0]; xf = eg[512]; xg = eg[1024]; xo = eg[1536];
    } else {
      xi = xb0; xf = xb1; xg = xb2; xo = xb3;
    }
    float ig = acc0[r] + xi, fg = acc1[r] + xf;
    float gg = acc2[r] + xg, og = acc3[r] + xo;
    size_t ci = (size_t)brow * HID + j;
    float cn = sigm(fg) * cst[ci] + sigm(ig) * tanh_f(gg);
    cst[ci] = cn;
    float hn = sigm(og) * tanh_f(cn);
    unsigned v = f2bf(hn);
    unsigned pv = (unsigned)__shfl_xor((int)v, 1);       // partner col
    if (!(lr & 1)){
      unsigned pack = (v & 0xFFFFu) | (pv << 16);        // cols (j, j+1)
      *(unsigned*)(hout + (size_t)brow * HID + j) = pack;
    }
  }
}

// ----------------------------------------------------- batched attention ----
__global__ void __launch_bounds__(256)
k_attn1(const unsigned short* __restrict__ fT, const unsigned short* __restrict__ h1r,
        float* __restrict__ d_out){
  int b = blockIdx.x, tid = threadIdx.x, w = tid >> 6, l = tid & 63;
  int lr = l & 15, lk = l >> 4;
  const unsigned short* fb = fT + (size_t)b * L_ * HID;
  v4f acc[2][4] = {};
  for (int ks = 0; ks < 16; ++ks){
    int kb = ks * 32 + lk * 8;
    v8bf a0 = ld8(h1r + ((size_t)(lr + 1)  * B_ + b) * HID + kb);   // t = lr
    v8bf a1 = ld8(h1r + ((size_t)(lr + 17) * B_ + b) * HID + kb);   // t = 16+lr
#pragma unroll
    for (int fn = 0; fn < 4; ++fn){
      v8bf bf = ld8(fb + (size_t)(w * 64 + fn * 16 + lr) * HID + kb);
      acc[0][fn] = __builtin_amdgcn_mfma_f32_16x16x32_bf16(a0, bf, acc[0][fn], 0, 0, 0);
      acc[1][fn] = __builtin_amdgcn_mfma_f32_16x16x32_bf16(a1, bf, acc[1][fn], 0, 0, 0);
    }
  }
#pragma unroll
  for (int fm = 0; fm < 2; ++fm)
#pragma unroll
    for (int fn = 0; fn < 4; ++fn)
#pragma unroll
      for (int r = 0; r < 4; ++r){
        int tt = fm * 16 + lk * 4 + r;
        int li = w * 64 + fn * 16 + lr;
        d_out[MASK_OFF + ((size_t)b * T_ + tt) * L_ + li] = sigm(acc[fm][fn][r]);
      }
}

__global__ void __launch_bounds__(512)
k_attn2(const unsigned short* __restrict__ fT, const float* __restrict__ d_out_ro,
        float* __restrict__ d_out, unsigned short* __restrict__ ctxbf){
  int b = blockIdx.x, tid = threadIdx.x, w = tid >> 6, l = tid & 63;
  __shared__ float aS[T_][L_];
  const float* ab = d_out_ro + MASK_OFF + (size_t)b * T_ * L_;
  for (int i = tid * 4; i < T_ * L_; i += 512 * 4){
    float4 v = *(const float4*)(ab + i);
    int tt = i >> 8, ll = i & 255;
    aS[tt][ll+0] = v.x; aS[tt][ll+1] = v.y; aS[tt][ll+2] = v.z; aS[tt][ll+3] = v.w;
  }
  __syncthreads();
  float acc[4][8] = {};
  const unsigned short* fb = fT + (size_t)b * L_ * HID + l * 8;
  for (int li = 0; li < L_; ++li){
    ushort4 u0 = *(const ushort4*)(fb + (size_t)li * HID);
    ushort4 u1 = *(const ushort4*)(fb + (size_t)li * HID + 4);
    float f[8] = {bf2f(u0.x), bf2f(u0.y), bf2f(u0.z), bf2f(u0.w),
                  bf2f(u1.x), bf2f(u1.y), bf2f(u1.z), bf2f(u1.w)};
#pragma unroll
    for (int tt = 0; tt < 4; ++tt){
      float a = aS[w * 4 + tt][li];
#pragma unroll
      for (int k = 0; k < 8; ++k) acc[tt][k] += a * f[k];
    }
  }
#pragma unroll
  for (int tt = 0; tt < 4; ++tt)
#pragma unroll
    for (int k = 0; k < 8; ++k){
      size_t o = ((size_t)b * T_ + w * 4 + tt) * HID + l * 8 + k;
      d_out[OH_OFF + o] = acc[tt][k];
      ctxbf[o] = f2bf(acc[tt][k]);
    }
}

// ------------------------------------------------------------------ final ---
__global__ void __launch_bounds__(256)
k_gen_m(const unsigned short* __restrict__ ctxbf, const unsigned short* __restrict__ genWbf,
        const float* __restrict__ genb, float* __restrict__ g){
  int m0 = blockIdx.x * 64 + (threadIdx.x >> 6) * 16;
  int j0 = blockIdx.y * 16;
  int l = threadIdx.x & 63, lr = l & 15, lk = l >> 4;
  int n = j0 + lr, nr = min(n, NC - 1);
  v4f acc = {0,0,0,0};
  for (int ks = 0; ks < 16; ++ks){
    int kb = ks * 32 + lk * 8;
    v8bf a  = ld8(ctxbf + (size_t)(m0 + lr) * HID + kb);
    v8bf bf = ld8(genWbf + (size_t)nr * HID + kb);
    acc = __builtin_amdgcn_mfma_f32_16x16x32_bf16(a, bf, acc, 0, 0, 0);
  }
  if (n < NC){
    float bb = genb[n];
#pragma unroll
    for (int r = 0; r < 4; ++r)
      g[(size_t)(m0 + lk * 4 + r) * NC + n] = acc[r] + bb;
  }
}

// --------------------------------------------------------------- fallbacks --
__global__ void __launch_bounds__(256)
k_attn_direct(const float* __restrict__ orig, const unsigned short* __restrict__ h1b,
              float* __restrict__ d_out, int t){
  int b = blockIdx.x, tid = threadIdx.x;
  __shared__ float h1s[HID];
  __shared__ float as[L_];
  h1s[tid]       = bf2f(h1b[(size_t)b * HID + tid]);
  h1s[256 + tid] = bf2f(h1b[(size_t)b * HID + 256 + tid]);
  __syncthreads();
  const float* fb = orig + (size_t)b * HID * L_;
  float dot = 0.f;
  for (int ch = 0; ch < HID; ++ch) dot += h1s[ch] * fb[(size_t)ch * L_ + tid];
  float a = sigm(dot);
  as[tid] = a;
  d_out[MASK_OFF + ((size_t)b * T_ + t) * L_ + tid] = a;
  __syncthreads();
  for (int cc = 0; cc < 2; ++cc){
    int ch = tid + cc * 256;
    float s = 0.f;
    for (int ll = 0; ll < L_; ++ll) s += as[ll] * fb[(size_t)ch * L_ + ll];
    d_out[OH_OFF + ((size_t)b * T_ + t) * HID + ch] = s;
  }
}

__global__ void k_gen_v(const float* __restrict__ ctx, const float* __restrict__ genW,
                        const float* __restrict__ genb, float* __restrict__ g){
  int o = blockIdx.x * 256 + threadIdx.x;
  if (o >= B_ * T_ * NC) return;
  int m = o / NC, n = o - m * NC;
  const float4* a = (const float4*)(ctx + (size_t)m * HID);
  const float4* wv = (const float4*)(genW + (size_t)n * HID);
  float s = genb[n];
  for (int k = 0; k < HID / 4; ++k){
    float4 av = a[k], w = wv[k];
    s += av.x * w.x + av.y * w.y + av.z * w.z + av.w * w.w;
  }
  g[o] = s;
}

// -----------------------------------------------------------------------------
extern "C" void kernel_launch(void* const* d_in, const int* in_sizes, int n_in,
                              void* d_out, int out_size, void* d_ws, size_t ws_size,
                              hipStream_t stream){
  const float* orig = (const float*)d_in[0];
  const int*   text = (const int*)  d_in[1];
  const float* embW = (const float*)d_in[2];
  const float* embb = (const float*)d_in[3];
  const float* Wih0 = (const float*)d_in[4];
  const float* Whh0 = (const float*)d_in[5];
  const float* bih0 = (const float*)d_in[6];
  const float* bhh0 = (const float*)d_in[7];
  const float* Wih1 = (const float*)d_in[8];
  const float* Whh1 = (const float*)d_in[9];
  const float* bih1 = (const float*)d_in[10];
  const float* bhh1 = (const float*)d_in[11];
  const float* genW = (const float*)d_in[12];
  const float* genb = (const float*)d_in[13];
  float* out = (float*)d_out;

  const size_t SLOTB = (size_t)B_ * HID * 2;          // 256 KB

  char* p = (char*)d_ws;
  float* embg  = (float*)p;           p += (size_t)NC * G4 * 4;
  float* b1sum = (float*)p;           p += (size_t)G4 * 4;
  // ---- zero-init region ----
  unsigned short* hx0 = (unsigned short*)p;    p += 2 * SLOTB;      // h0 ping-pong
  float* c0 = (float*)p;                       p += (size_t)B_ * HID * 4;
  float* c1 = (float*)p;                       p += (size_t)B_ * HID * 4;
  size_t zbytes = (size_t)((char*)p - (char*)hx0);
  // ---- end zero region ----
  unsigned short* Whh0bf  = (unsigned short*)p; p += (size_t)G4 * 512 * 2;
  unsigned short* Wcat1bf = (unsigned short*)p; p += (size_t)G4 * 1024 * 2;
  unsigned short* Wih0bf  = (unsigned short*)p; p += (size_t)G4 * 512 * 2;
  unsigned short* embXbf  = (unsigned short*)p; p += (size_t)NC * HID * 2;
  unsigned short* genWbf  = (unsigned short*)p; p += (size_t)NC * HID * 2;
  unsigned short* h1r = (unsigned short*)p;    p += 33 * SLOTB;     // h1 ring (8.25MB)
  unsigned short* ctxbf = (unsigned short*)p;  p += (size_t)B_ * T_ * HID * 2;  // 8MB
  unsigned short* fmapT = (unsigned short*)p;  p += (size_t)B_ * L_ * HID * 2;  // 64MB
  bool big = ws_size >= (size_t)(p - (char*)d_ws);

  hipMemsetAsync(hx0, 0, zbytes, stream);
  hipMemsetAsync(h1r, 0, SLOTB, stream);              // h1(0) = zeros

  k_wconv<<<(G4 * HID + 255) / 256, 256, 0, stream>>>(Whh0, Wih1, Whh1, Wih0,
                                                      Whh0bf, Wcat1bf, Wih0bf);
  k_small<<<(NC * HID + 255) / 256, 256, 0, stream>>>(embW, embb, genW, bih1, bhh1,
                                                      embXbf, genWbf, b1sum);
  k_embg_m<<<dim3(7, G4 / 16), 64, 0, stream>>>(embXbf, Wih0bf, bih0, bhh0, embg);
  if (big) k_fmapT<<<dim3(L_ / 32, HID / 32, B_), dim3(32, 8), 0, stream>>>(orig, fmapT);

  // ---- the recurrence: 33 fused pipelined launches, no in-kernel sync ----
  for (int pp = 0; pp <= 32; ++pp)
    k_step<<<256, 256, 0, stream>>>(Whh0bf, Wcat1bf, embg, text, b1sum,
                                    hx0, h1r, c0, c1, pp);

  if (big){
    k_attn1<<<B_, 256, 0, stream>>>(fmapT, h1r, out);
    k_attn2<<<B_, 512, 0, stream>>>(fmapT, (const float*)out, out, ctxbf);
    k_gen_m<<<dim3(B_ * T_ / 64, 7), 256, 0, stream>>>(ctxbf, genWbf, genb, out);
  } else {
    for (int t = 0; t < T_; ++t)
      k_attn_direct<<<B_, 256, 0, stream>>>(orig, h1r + (size_t)(t + 1) * B_ * HID,
                                            out, t);
    k_gen_v<<<(B_ * T_ * NC + 255) / 256, 256, 0, stream>>>(out + OH_OFF, genW, genb, out);
  }
}

// Round 11
// 624.646 us; speedup vs baseline: 5490.0966x; 1.2144x over previous
//
#include <hip/hip_runtime.h>

#define B_   256
#define HID  512
#define T_   32
#define L_   256
#define NC   97
#define G4   2048

// d_out layout (f32): g [256,32,97] | output_hiddens [256,32,512] | masks [256,32,8,32]
#define OH_OFF   794624
#define MASK_OFF 4988928

typedef __bf16 v8bf __attribute__((ext_vector_type(8)));
typedef float  v4f  __attribute__((ext_vector_type(4)));
typedef unsigned int v4u __attribute__((ext_vector_type(4)));

__device__ __forceinline__ unsigned short f2bf(float x){
  unsigned u = __float_as_uint(x);
  u += 0x7FFFu + ((u >> 16) & 1u);          // round-to-nearest-even
  return (unsigned short)(u >> 16);
}
__device__ __forceinline__ float bf2f(unsigned short h){
  return __uint_as_float(((unsigned)h) << 16);
}
__device__ __forceinline__ float sigm(float x){ return 1.f / (1.f + __expf(-x)); }
__device__ __forceinline__ float tanh_f(float x){
  float e = __expf(2.f * x);
  return 1.f - 2.f / (e + 1.f);             // safe at +/-inf
}
__device__ __forceinline__ v8bf ld8(const unsigned short* p){
  return *reinterpret_cast<const v8bf*>(p);
}

// ---------------------------------------------------------------- one-time --
__global__ void k_wconv(const float* __restrict__ Whh0, const float* __restrict__ Wih1,
                        const float* __restrict__ Whh1, const float* __restrict__ Wih0,
                        unsigned short* __restrict__ Whh0bf, unsigned short* __restrict__ Wcat1bf,
                        unsigned short* __restrict__ Wih0bf){
  int i = blockIdx.x * 256 + threadIdx.x;
  if (i >= G4 * HID) return;
  Whh0bf[i] = f2bf(Whh0[i]);
  Wih0bf[i] = f2bf(Wih0[i]);
  int n = i >> 9, k = i & 511;
  Wcat1bf[(size_t)n * 1024 + k]       = f2bf(Wih1[i]);
  Wcat1bf[(size_t)n * 1024 + 512 + k] = f2bf(Whh1[i]);
}

__global__ void k_small(const float* __restrict__ embW, const float* __restrict__ embb,
                        const float* __restrict__ genW, const float* __restrict__ bih1,
                        const float* __restrict__ bhh1,
                        unsigned short* __restrict__ embXbf, unsigned short* __restrict__ genWbf,
                        float* __restrict__ b1sum){
  int i = blockIdx.x * 256 + threadIdx.x;
  if (i < NC * HID){
    int c = i >> 9, h = i & 511;
    embXbf[i] = f2bf(embW[h * NC + c] + embb[h]);
    genWbf[i] = f2bf(genW[i]);
  }
  if (i < G4) b1sum[i] = bih1[i] + bhh1[i];
}

// emb_gates[c][n] (MFMA, M=97 N=2048 K=512)
__global__ void __launch_bounds__(64)
k_embg_m(const unsigned short* __restrict__ embXbf, const unsigned short* __restrict__ Wih0bf,
         const float* __restrict__ bih0, const float* __restrict__ bhh0,
         float* __restrict__ embg){
  int m0 = blockIdx.x * 16, j0 = blockIdx.y * 16;
  int l = threadIdx.x, lr = l & 15, lk = l >> 4;
  int ar = min(m0 + lr, NC - 1);
  v4f acc = {0,0,0,0};
  for (int ks = 0; ks < 16; ++ks){
    int kb = ks * 32 + lk * 8;
    v8bf a  = ld8(embXbf + (size_t)ar * HID + kb);
    v8bf bf = ld8(Wih0bf + (size_t)(j0 + lr) * HID + kb);
    acc = __builtin_amdgcn_mfma_f32_16x16x32_bf16(a, bf, acc, 0, 0, 0);
  }
  int n = j0 + lr;
  float bb = bih0[n] + bhh0[n];
#pragma unroll
  for (int r = 0; r < 4; ++r){
    int c = m0 + lk * 4 + r;
    if (c < NC) embg[(size_t)c * G4 + n] = acc[r] + bb;
  }
}

// origin[b][c][l] f32 -> fmapT[b][l][c] bf16
__global__ void k_fmapT(const float* __restrict__ orig, unsigned short* __restrict__ fT){
  __shared__ float tile[32][33];
  int b = blockIdx.z, c0 = blockIdx.y * 32, l0 = blockIdx.x * 32;
  const float* src = orig + ((size_t)b * HID + c0) * L_ + l0;
  for (int i = 0; i < 32; i += 8)
    tile[threadIdx.y + i][threadIdx.x] = src[(threadIdx.y + i) * L_ + threadIdx.x];
  __syncthreads();
  unsigned short* dst = fT + ((size_t)b * L_ + l0) * HID + c0;
  for (int i = 0; i < 32; i += 8)
    dst[(threadIdx.y + i) * HID + threadIdx.x] = f2bf(tile[threadIdx.x][threadIdx.y + i]);
}

// ----------------------------------------------- fused per-step LSTM launch --
// Launched 33x (p = 0..32). Blocks 0..511: LSTM0 step p (skip if p==32).
// Blocks 512..1023: LSTM1 step p-1 (skip if p==0). Kernel boundary provides
// all producer->consumer coherence: plain loads/stores only.
// GATE-SPLIT occupancy design (round-10 lesson: every structure bottomed at
// ~18us/step because only 4 waves/CU were resident -- latency, not BW):
// block = 16 rows x 16 j-cols, wave w computes gate w. 1024 blocks/launch
// -> 4 blocks/CU (LDS 37.6KB), 16 waves/CU, 4/SIMD: weight-load latency is
// hidden by wave overlap. Weight traffic unchanged; same-j blocks co-reside
// per XCD so weight slices go L2-resident across the 16 bands.
// Cell epilogue merges the 4 gates via a 4KB LDS gbuf, 1 element/thread.
__global__ void __launch_bounds__(256)
k_step2(const unsigned short* __restrict__ Whh0bf,
        const unsigned short* __restrict__ Wcat1bf,
        const float* __restrict__ embg, const int* __restrict__ text,
        const float* __restrict__ b1sum,
        unsigned short* __restrict__ hx0, unsigned short* __restrict__ h1r,
        float* __restrict__ c0, float* __restrict__ c1, int p){
  const int SLOT = B_ * HID;
  const int bid = blockIdx.x;
  const bool isB = bid >= 512;
  if (isB ? (p < 1) : (p >= 32)) return;
  const int gb = bid & 511;
  const int band = gb >> 5;                  // 0..15
  const int jg   = gb & 31;                  // 0..31
  const int m0 = band * 16;
  const int j0 = jg * 16;
  const int tid = threadIdx.x;
  const int w = tid >> 6, l = tid & 63, lr = l & 15, lk = l >> 4;
  const int t = isB ? (p - 1) : p;

  __shared__ unsigned short hS[16][1048];    // A: cols 0..511; B: h0|h1 0..1023
  __shared__ float gbuf[4][16][16];          // gate exchange

  const unsigned short* hA = hx0 + (size_t)(p & 1) * SLOT;              // h0(p)
  const unsigned short* hB = h1r + (size_t)(isB ? (p - 1) : 0) * SLOT;  // h1(p-1)

  if (isB){
#pragma unroll
    for (int i = 0; i < 8; ++i){
      int e = tid + 256 * i;                 // 0..2047 (16B chunks)
      int part = e >> 10, ei = e & 1023;
      int row = ei >> 6, c8 = (ei & 63) * 8;
      const unsigned short* src = (part ? hB : hA) + (size_t)(m0 + row) * HID + c8;
      *(v4u*)&hS[row][part * 512 + c8] = *(const v4u*)src;
    }
  } else {
#pragma unroll
    for (int i = 0; i < 4; ++i){
      int e = tid + 256 * i;                 // 0..1023
      int row = e >> 6, c8 = (e & 63) * 8;
      *(v4u*)&hS[row][c8] = *(const v4u*)(hA + (size_t)(m0 + row) * HID + c8);
    }
  }
  __syncthreads();

  // ---- MFMA: wave w computes gate w over 16 rows x 16 j, full K
  const unsigned short* W = isB ? Wcat1bf : Whh0bf;
  const int wstr = isB ? 1024 : 512;
  const int KS   = isB ? 32 : 16;
  const unsigned short* wrow = W + (size_t)(w * HID + j0 + lr) * wstr;
  v4f acc = {0,0,0,0};
#pragma unroll 4
  for (int ks = 0; ks < KS; ++ks){
    const int kb = ks * 32 + lk * 8;
    v8bf a  = *(const v8bf*)&hS[lr][kb];
    v8bf bf = ld8(wrow + kb);
    acc = __builtin_amdgcn_mfma_f32_16x16x32_bf16(a, bf, acc, 0, 0, 0);
  }
#pragma unroll
  for (int r = 0; r < 4; ++r)
    gbuf[w][lk * 4 + r][lr] = acc[r];        // D: row=(l>>4)*4+r, col=l&15
  __syncthreads();

  // ---- cell epilogue: one output element per thread
  {
    const int row = tid >> 4, col = tid & 15;
    const int brow = m0 + row, j = j0 + col;
    float xi, xf, xg, xo;
    if (!isB){
      const float* eg = embg + (size_t)text[brow * T_ + t] * G4 + j;
      xi = eg[0]; xf = eg[512]; xg = eg[1024]; xo = eg[1536];
    } else {
      xi = b1sum[j]; xf = b1sum[512 + j];
      xg = b1sum[1024 + j]; xo = b1sum[1536 + j];
    }
    float ig = gbuf[0][row][col] + xi, fg = gbuf[1][row][col] + xf;
    float gg = gbuf[2][row][col] + xg, og = gbuf[3][row][col] + xo;
    float* cst = isB ? c1 : c0;
    size_t ci = (size_t)brow * HID + j;
    float cn = sigm(fg) * cst[ci] + sigm(ig) * tanh_f(gg);
    cst[ci] = cn;
    float hn = sigm(og) * tanh_f(cn);
    unsigned short* hout = isB ? (h1r + (size_t)p * SLOT)             // h1(p)
                               : (hx0 + (size_t)((p + 1) & 1) * SLOT);// h0(p+1)
    unsigned v = f2bf(hn);
    unsigned pv = (unsigned)__shfl_xor((int)v, 1);       // partner col
    if (!(tid & 1)){
      unsigned pack = (v & 0xFFFFu) | (pv << 16);        // cols (j, j+1)
      *(unsigned*)(hout + (size_t)brow * HID + j) = pack;
    }
  }
}

// ----------------------------------------------------- batched attention ----
__global__ void __launch_bounds__(256)
k_attn1(const unsigned short* __restrict__ fT, const unsigned short* __restrict__ h1r,
        float* __restrict__ d_out){
  int b = blockIdx.x, tid = threadIdx.x, w = tid >> 6, l = tid & 63;
  int lr = l & 15, lk = l >> 4;
  const unsigned short* fb = fT + (size_t)b * L_ * HID;
  v4f acc[2][4] = {};
  for (int ks = 0; ks < 16; ++ks){
    int kb = ks * 32 + lk * 8;
    v8bf a0 = ld8(h1r + ((size_t)(lr + 1)  * B_ + b) * HID + kb);   // t = lr
    v8bf a1 = ld8(h1r + ((size_t)(lr + 17) * B_ + b) * HID + kb);   // t = 16+lr
#pragma unroll
    for (int fn = 0; fn < 4; ++fn){
      v8bf bf = ld8(fb + (size_t)(w * 64 + fn * 16 + lr) * HID + kb);
      acc[0][fn] = __builtin_amdgcn_mfma_f32_16x16x32_bf16(a0, bf, acc[0][fn], 0, 0, 0);
      acc[1][fn] = __builtin_amdgcn_mfma_f32_16x16x32_bf16(a1, bf, acc[1][fn], 0, 0, 0);
    }
  }
#pragma unroll
  for (int fm = 0; fm < 2; ++fm)
#pragma unroll
    for (int fn = 0; fn < 4; ++fn)
#pragma unroll
      for (int r = 0; r < 4; ++r){
        int tt = fm * 16 + lk * 4 + r;
        int li = w * 64 + fn * 16 + lr;
        d_out[MASK_OFF + ((size_t)b * T_ + tt) * L_ + li] = sigm(acc[fm][fn][r]);
      }
}

__global__ void __launch_bounds__(512)
k_attn2(const unsigned short* __restrict__ fT, const float* __restrict__ d_out_ro,
        float* __restrict__ d_out, unsigned short* __restrict__ ctxbf){
  int b = blockIdx.x, tid = threadIdx.x, w = tid >> 6, l = tid & 63;
  __shared__ float aS[T_][L_];
  const float* ab = d_out_ro + MASK_OFF + (size_t)b * T_ * L_;
  for (int i = tid * 4; i < T_ * L_; i += 512 * 4){
    float4 v = *(const float4*)(ab + i);
    int tt = i >> 8, ll = i & 255;
    aS[tt][ll+0] = v.x; aS[tt][ll+1] = v.y; aS[tt][ll+2] = v.z; aS[tt][ll+3] = v.w;
  }
  __syncthreads();
  float acc[4][8] = {};
  const unsigned short* fb = fT + (size_t)b * L_ * HID + l * 8;
  for (int li = 0; li < L_; ++li){
    ushort4 u0 = *(const ushort4*)(fb + (size_t)li * HID);
    ushort4 u1 = *(const ushort4*)(fb + (size_t)li * HID + 4);
    float f[8] = {bf2f(u0.x), bf2f(u0.y), bf2f(u0.z), bf2f(u0.w),
                  bf2f(u1.x), bf2f(u1.y), bf2f(u1.z), bf2f(u1.w)};
#pragma unroll
    for (int tt = 0; tt < 4; ++tt){
      float a = aS[w * 4 + tt][li];
#pragma unroll
      for (int k = 0; k < 8; ++k) acc[tt][k] += a * f[k];
    }
  }
#pragma unroll
  for (int tt = 0; tt < 4; ++tt)
#pragma unroll
    for (int k = 0; k < 8; ++k){
      size_t o = ((size_t)b * T_ + w * 4 + tt) * HID + l * 8 + k;
      d_out[OH_OFF + o] = acc[tt][k];
      ctxbf[o] = f2bf(acc[tt][k]);
    }
}

// ------------------------------------------------------------------ final ---
__global__ void __launch_bounds__(256)
k_gen_m(const unsigned short* __restrict__ ctxbf, const unsigned short* __restrict__ genWbf,
        const float* __restrict__ genb, float* __restrict__ g){
  int m0 = blockIdx.x * 64 + (threadIdx.x >> 6) * 16;
  int j0 = blockIdx.y * 16;
  int l = threadIdx.x & 63, lr = l & 15, lk = l >> 4;
  int n = j0 + lr, nr = min(n, NC - 1);
  v4f acc = {0,0,0,0};
  for (int ks = 0; ks < 16; ++ks){
    int kb = ks * 32 + lk * 8;
    v8bf a  = ld8(ctxbf + (size_t)(m0 + lr) * HID + kb);
    v8bf bf = ld8(genWbf + (size_t)nr * HID + kb);
    acc = __builtin_amdgcn_mfma_f32_16x16x32_bf16(a, bf, acc, 0, 0, 0);
  }
  if (n < NC){
    float bb = genb[n];
#pragma unroll
    for (int r = 0; r < 4; ++r)
      g[(size_t)(m0 + lk * 4 + r) * NC + n] = acc[r] + bb;
  }
}

// --------------------------------------------------------------- fallbacks --
__global__ void __launch_bounds__(256)
k_attn_direct(const float* __restrict__ orig, const unsigned short* __restrict__ h1b,
              float* __restrict__ d_out, int t){
  int b = blockIdx.x, tid = threadIdx.x;
  __shared__ float h1s[HID];
  __shared__ float as[L_];
  h1s[tid]       = bf2f(h1b[(size_t)b * HID + tid]);
  h1s[256 + tid] = bf2f(h1b[(size_t)b * HID + 256 + tid]);
  __syncthreads();
  const float* fb = orig + (size_t)b * HID * L_;
  float dot = 0.f;
  for (int ch = 0; ch < HID; ++ch) dot += h1s[ch] * fb[(size_t)ch * L_ + tid];
  float a = sigm(dot);
  as[tid] = a;
  d_out[MASK_OFF + ((size_t)b * T_ + t) * L_ + tid] = a;
  __syncthreads();
  for (int cc = 0; cc < 2; ++cc){
    int ch = tid + cc * 256;
    float s = 0.f;
    for (int ll = 0; ll < L_; ++ll) s += as[ll] * fb[(size_t)ch * L_ + ll];
    d_out[OH_OFF + ((size_t)b * T_ + t) * HID + ch] = s;
  }
}

__global__ void k_gen_v(const float* __restrict__ ctx, const float* __restrict__ genW,
                        const float* __restrict__ genb, float* __restrict__ g){
  int o = blockIdx.x * 256 + threadIdx.x;
  if (o >= B_ * T_ * NC) return;
  int m = o / NC, n = o - m * NC;
  const float4* a = (const float4*)(ctx + (size_t)m * HID);
  const float4* wv = (const float4*)(genW + (size_t)n * HID);
  float s = genb[n];
  for (int k = 0; k < HID / 4; ++k){
    float4 av = a[k], w = wv[k];
    s += av.x * w.x + av.y * w.y + av.z * w.z + av.w * w.w;
  }
  g[o] = s;
}

// -----------------------------------------------------------------------------
extern "C" void kernel_launch(void* const* d_in, const int* in_sizes, int n_in,
                              void* d_out, int out_size, void* d_ws, size_t ws_size,
                              hipStream_t stream){
  const float* orig = (const float*)d_in[0];
  const int*   text = (const int*)  d_in[1];
  const float* embW = (const float*)d_in[2];
  const float* embb = (const float*)d_in[3];
  const float* Wih0 = (const float*)d_in[4];
  const float* Whh0 = (const float*)d_in[5];
  const float* bih0 = (const float*)d_in[6];
  const float* bhh0 = (const float*)d_in[7];
  const float* Wih1 = (const float*)d_in[8];
  const float* Whh1 = (const float*)d_in[9];
  const float* bih1 = (const float*)d_in[10];
  const float* bhh1 = (const float*)d_in[11];
  const float* genW = (const float*)d_in[12];
  const float* genb = (const float*)d_in[13];
  float* out = (float*)d_out;

  const size_t SLOTB = (size_t)B_ * HID * 2;          // 256 KB

  char* p = (char*)d_ws;
  float* embg  = (float*)p;           p += (size_t)NC * G4 * 4;
  float* b1sum = (float*)p;           p += (size_t)G4 * 4;
  // ---- zero-init region ----
  unsigned short* hx0 = (unsigned short*)p;    p += 2 * SLOTB;      // h0 ping-pong
  float* c0 = (float*)p;                       p += (size_t)B_ * HID * 4;
  float* c1 = (float*)p;                       p += (size_t)B_ * HID * 4;
  size_t zbytes = (size_t)((char*)p - (char*)hx0);
  // ---- end zero region ----
  unsigned short* Whh0bf  = (unsigned short*)p; p += (size_t)G4 * 512 * 2;
  unsigned short* Wcat1bf = (unsigned short*)p; p += (size_t)G4 * 1024 * 2;
  unsigned short* Wih0bf  = (unsigned short*)p; p += (size_t)G4 * 512 * 2;
  unsigned short* embXbf  = (unsigned short*)p; p += (size_t)NC * HID * 2;
  unsigned short* genWbf  = (unsigned short*)p; p += (size_t)NC * HID * 2;
  unsigned short* h1r = (unsigned short*)p;    p += 33 * SLOTB;     // h1 ring (8.25MB)
  unsigned short* ctxbf = (unsigned short*)p;  p += (size_t)B_ * T_ * HID * 2;  // 8MB
  unsigned short* fmapT = (unsigned short*)p;  p += (size_t)B_ * L_ * HID * 2;  // 64MB
  bool big = ws_size >= (size_t)(p - (char*)d_ws);

  hipMemsetAsync(hx0, 0, zbytes, stream);
  hipMemsetAsync(h1r, 0, SLOTB, stream);              // h1(0) = zeros

  k_wconv<<<(G4 * HID + 255) / 256, 256, 0, stream>>>(Whh0, Wih1, Whh1, Wih0,
                                                      Whh0bf, Wcat1bf, Wih0bf);
  k_small<<<(NC * HID + 255) / 256, 256, 0, stream>>>(embW, embb, genW, bih1, bhh1,
                                                      embXbf, genWbf, b1sum);
  k_embg_m<<<dim3(7, G4 / 16), 64, 0, stream>>>(embXbf, Wih0bf, bih0, bhh0, embg);
  if (big) k_fmapT<<<dim3(L_ / 32, HID / 32, B_), dim3(32, 8), 0, stream>>>(orig, fmapT);

  // ---- the recurrence: 33 fused pipelined launches, no in-kernel sync ----
  for (int pp = 0; pp <= 32; ++pp)
    k_step2<<<1024, 256, 0, stream>>>(Whh0bf, Wcat1bf, embg, text, b1sum,
                                      hx0, h1r, c0, c1, pp);

  if (big){
    k_attn1<<<B_, 256, 0, stream>>>(fmapT, h1r, out);
    k_attn2<<<B_, 512, 0, stream>>>(fmapT, (const float*)out, out, ctxbf);
    k_gen_m<<<dim3(B_ * T_ / 64, 7), 256, 0, stream>>>(ctxbf, genWbf, genb, out);
  } else {
    for (int t = 0; t < T_; ++t)
      k_attn_direct<<<B_, 256, 0, stream>>>(orig, h1r + (size_t)(t + 1) * B_ * HID,
                                            out, t);
    k_gen_v<<<(B_ * T_ * NC + 255) / 256, 256, 0, stream>>>(out + OH_OFF, genW, genb, out);
  }
}